// Round 5
// baseline (292.833 us; speedup 1.0000x reference)
//
#include <hip/hip_runtime.h>
#include <math.h>

// GCN forward, CSR-gather; bf16 xs/W2/ht1; MFMA layer-2 dense; block-
// aggregated pooling. CSR build = single-pass fixed-capacity bucket sort
// (see earlier round notes). Requires N <= 65536.
// Pipeline (6 dispatches):
//   memset    : bcnt = 0 (784 B)
//   k_bfill   : per-block LDS hist + reservation -> col1; tails: gsum=0,
//               gptr, W2bf=bf16(W2^T)
//   k_bsort   : per-bucket LDS sort -> rowptr, dinv, col; xsb=bf16(x*dinv)
//   k_l12g    : gather rank-16 -> h1=relu -> MFMA -> ht1b bf16
//   k_gatslice: layer-2 gather, FEATURE-SLICE-PER-XCD (R4): block b does
//               slice s=b&7 (16 dims, 32B/row) of node-block b>>3 (32
//               nodes). Round-robin blockIdx->XCD puts one slice on each
//               XCD -> per-XCD touched ht1b bytes = N x 64B sector
//               ~3.2MB <= 4MB L2 -> slice L2-resident. R3/R4 established:
//               fetch is capacity-driven (split halved it to the 102MB
//               compulsory floor) but a 2nd traversal costs ~32us; this
//               gets the fetch cut in ONE traversal (same instr count:
//               1KB/instr = 32 edges x 32B). col/rowptr re-read 8x -> L3.
//   k_head    : pooled = gsum/cnt; label/domain heads

#define BCAP 12288   // bucket capacity (mean fill ~8.2K, 45 sigma headroom)

typedef __attribute__((ext_vector_type(8))) short short8;   // 8 bf16 (4 VGPRs)
typedef __attribute__((ext_vector_type(4))) float f32x4;    // MFMA accumulator

__device__ __forceinline__ void bf4acc(uint2 u, float* a) {
    a[0] += __uint_as_float(u.x << 16);
    a[1] += __uint_as_float(u.x & 0xffff0000u);
    a[2] += __uint_as_float(u.y << 16);
    a[3] += __uint_as_float(u.y & 0xffff0000u);
}

__device__ __forceinline__ void bf8acc(uint4 u, float* a) {
    a[0] += __uint_as_float(u.x << 16);
    a[1] += __uint_as_float(u.x & 0xffff0000u);
    a[2] += __uint_as_float(u.y << 16);
    a[3] += __uint_as_float(u.y & 0xffff0000u);
    a[4] += __uint_as_float(u.z << 16);
    a[5] += __uint_as_float(u.z & 0xffff0000u);
    a[6] += __uint_as_float(u.w << 16);
    a[7] += __uint_as_float(u.w & 0xffff0000u);
}

__device__ __forceinline__ unsigned short bf1(float a) {    // RNE bf16
    unsigned ua = __float_as_uint(a);
    return (unsigned short)((ua + 0x7fffu + ((ua >> 16) & 1u)) >> 16);
}

// ---- single-pass bucketed fill + prep tails ----
__global__ __launch_bounds__(256) void k_bfill(
        const int* __restrict__ ei, int* __restrict__ bcnt,
        unsigned* __restrict__ col1,
        const int* __restrict__ batch, int* __restrict__ gptr,
        float* __restrict__ gsum, const float* __restrict__ W2,
        unsigned short* __restrict__ W2bf,
        int E, int chunk, int NB, int N, int G) {
    __shared__ int bins[256];
    __shared__ int base[256];
    for (int t = threadIdx.x; t < NB; t += 256) bins[t] = 0;
    __syncthreads();
    const int e0 = blockIdx.x * chunk;
    int e1 = e0 + chunk; if (e1 > E) e1 = E;
    for (int j = e0 + (int)threadIdx.x; j < e1; j += 256)
        atomicAdd(&bins[ei[E + j] >> 8], 1);
    __syncthreads();
    for (int t = threadIdx.x; t < NB; t += 256) {
        base[t] = bins[t] ? atomicAdd(&bcnt[t], bins[t]) : 0;
        bins[t] = 0;
    }
    __syncthreads();
    for (int j = e0 + (int)threadIdx.x; j < e1; j += 256) {
        int d = ei[E + j];              // L2-warm (read in hist pass)
        int s = ei[j];
        int b = d >> 8;
        int pos = base[b] + atomicAdd(&bins[b], 1);
        if (pos < BCAP)
            col1[(size_t)b * BCAP + pos] = ((unsigned)(d & 255) << 16) | (unsigned)s;
    }

    // distributed prep tails
    const int gid = blockIdx.x * 256 + threadIdx.x;
    const int gsz = gridDim.x * 256;
    for (int i = gid; i < G * 32; i += gsz)        // gsum = 0 (float4)
        ((float4*)gsum)[i] = make_float4(0.f, 0.f, 0.f, 0.f);
    for (int i = gid; i < 16384; i += gsz) {       // W2bf[f2][f1] = bf16(W2[f1][f2])
        const int f2 = i >> 7, f1 = i & 127;
        W2bf[i] = bf1(W2[f1 * 128 + f2]);
    }
    for (int g = gid; g <= G; g += gsz) {          // gptr = lower_bound(batch,g)
        int lo = 0, hi = N;
        while (lo < hi) {
            int mid = (lo + hi) >> 1;
            if (batch[mid] < g) lo = mid + 1; else hi = mid;
        }
        gptr[g] = lo;
    }
}

// ---- per-bucket LDS sort -> exact CSR + dinv + xsb (self-scans bcnt) ----
__global__ __launch_bounds__(256) void k_bsort(const unsigned* __restrict__ col1,
                                               const int* __restrict__ bcnt,
                                               int* __restrict__ col,
                                               int* __restrict__ rowptr,
                                               float* __restrict__ dinv,
                                               const float* __restrict__ x,
                                               unsigned short* __restrict__ xsb,
                                               int N, int E, int NB) {
    __shared__ unsigned ec[BCAP];
    __shared__ int bins[256], sc[256];
    __shared__ float dvb[256];
    const int b = blockIdx.x, t = threadIdx.x;

    // bucket-offset scan (196 ints, L2-hot): s0 = sum_{i<b} bcnt[i]
    {
        int v = (t < NB) ? bcnt[t] : 0;
        bins[t] = v;
        __syncthreads();
        for (int off = 1; off < 256; off <<= 1) {
            int add = (t >= off) ? bins[t - off] : 0;
            __syncthreads();
            bins[t] += add;
            __syncthreads();
        }
    }
    const int s0 = (b == 0) ? 0 : bins[b - 1];
    int cnt = bcnt[b];
    if (cnt > BCAP) cnt = BCAP;        // safety clamp (never hit for this E,N)
    __syncthreads();

    for (int i = t; i < cnt; i += 256) ec[i] = col1[(size_t)b * BCAP + i];
    bins[t] = 0;
    __syncthreads();
    for (int i = t; i < cnt; i += 256) atomicAdd(&bins[ec[i] >> 16], 1);
    __syncthreads();
    const int v = bins[t];
    sc[t] = v;
    __syncthreads();
    for (int off = 1; off < 256; off <<= 1) {
        int add = (t >= off) ? sc[t - off] : 0;
        __syncthreads();
        sc[t] += add;
        __syncthreads();
    }
    const int ex = sc[t] - v;
    __syncthreads();
    sc[t] = ex;          // exclusive local offsets
    bins[t] = 0;         // reuse as per-node cursor
    const float dv = rsqrtf((float)(v + 1));
    dvb[t] = dv;
    const int n0 = b * 256;
    if (n0 + t < N) {
        rowptr[n0 + t] = s0 + ex;
        dinv[n0 + t] = dv;
    }
    if (b == 0 && t == 0) rowptr[N] = E;
    __syncthreads();
    for (int i = t; i < cnt; i += 256) {
        unsigned e = ec[i];
        int dl = e >> 16;
        int p = sc[dl] + atomicAdd(&bins[dl], 1);
        col[s0 + p] = (int)(e & 0xffffu);
    }
    // xsb = bf16(x * dinv) for this bucket's nodes (coalesced)
    int nn = N - n0; if (nn > 256) nn = 256;
    const int lim = nn * 16;
    for (int i = t; i < lim; i += 256) {
        float vx = x[(size_t)n0 * 16 + i] * dvb[i >> 4];
        xsb[(size_t)n0 * 16 + i] = bf1(vx);
    }
}

// ---- FUSED gat16 + l12 (MFMA): 64 nodes/block, 512 threads (8 waves),
//      ~57 KB LDS -> 2 blocks/CU.
__global__ __launch_bounds__(512, 4) void k_l12g(
        const int* __restrict__ rowptr, const int* __restrict__ col,
        const unsigned short* __restrict__ xsb,
        const float* __restrict__ dinv,
        const float* __restrict__ W1, const float* __restrict__ b1,
        const unsigned short* __restrict__ W2bf,   // [f2][f1] bf16
        unsigned short* __restrict__ ht1b, int N) {
    __shared__ __align__(16) unsigned short W2s[128 * 136];  // [f2][f1] padded
    __shared__ __align__(16) unsigned short h1b[64 * 136];   // [node][f1] padded
    __shared__ __align__(16) float arow[64 * 16];
    __shared__ float dv[64];
    const int tid = threadIdx.x;
    const int n0 = blockIdx.x * 64;
    const int w = tid >> 6, lane = tid & 63;

    // stage W2^T (bf16): 128 rows x 16 uint4 segments
    for (int i = tid; i < 2048; i += 512) {
        const int f2 = i >> 4, seg = i & 15;
        *(uint4*)&W2s[f2 * 136 + seg * 8] = ((const uint4*)W2bf)[i];
    }
    if (tid < 64) dv[tid] = (n0 + tid < N) ? dinv[n0 + tid] : 0.f;

    // gather: 8 lanes per node (2 edge slots x 4 quarters), 8 nodes per wave
    {
        const int nd = lane >> 3, sub = lane & 7;
        const int slot = sub >> 2, qq = sub & 3;
        const int j = w * 8 + nd;
        const int n = n0 + j;
        float a[4] = {0.f, 0.f, 0.f, 0.f};
        if (n < N) {
            const int r1 = rowptr[n + 1];
            for (int e = rowptr[n] + slot; e < r1; e += 2)
                bf4acc(*(const uint2*)(xsb + (size_t)col[e] * 16 + qq * 4), a);
        }
#pragma unroll
        for (int i = 0; i < 4; ++i) a[i] += __shfl_xor(a[i], 4);
        if (slot == 0) {
            if (n < N) {   // self loop
                bf4acc(*(const uint2*)(xsb + (size_t)n * 16 + qq * 4), a);
                *(float4*)&arow[j * 16 + qq * 4] = make_float4(a[0], a[1], a[2], a[3]);
            } else {
                *(float4*)&arow[j * 16 + qq * 4] = make_float4(0.f, 0.f, 0.f, 0.f);
            }
        }
    }
    const int f = tid & 127, jg = tid >> 7;
    float w1r[16];
#pragma unroll
    for (int k = 0; k < 16; ++k) w1r[k] = W1[k * 128 + f];
    const float bias = b1[f];
    __syncthreads();

    // phase 1: h1 (bf16) into A-layout LDS
#pragma unroll 4
    for (int j = jg * 16; j < jg * 16 + 16; ++j) {
        float s = 0.f;
#pragma unroll
        for (int k = 0; k < 16; ++k) s += arow[j * 16 + k] * w1r[k];
        h1b[j * 136 + f] = bf1(fmaxf(dv[j] * s + bias, 0.f));
    }
    __syncthreads();

    // phase 2: MFMA, D[64x128] = h1[64x128] @ W2[128x128]
    const int mt = w & 3, nh = w >> 2;
    const int lm = lane & 15, quad = lane >> 4;
    f32x4 acc[4];
#pragma unroll
    for (int t = 0; t < 4; ++t) acc[t] = (f32x4){0.f, 0.f, 0.f, 0.f};
#pragma unroll
    for (int kb = 0; kb < 4; ++kb) {
        const short8 af = *(const short8*)&h1b[(mt * 16 + lm) * 136 + kb * 32 + quad * 8];
#pragma unroll
        for (int t = 0; t < 4; ++t) {
            const short8 bfv = *(const short8*)&W2s[(nh * 64 + t * 16 + lm) * 136 + kb * 32 + quad * 8];
            acc[t] = __builtin_amdgcn_mfma_f32_16x16x32_bf16(af, bfv, acc[t], 0, 0, 0);
        }
    }
    // epilogue: *dinv, pack bf16, store
#pragma unroll
    for (int t = 0; t < 4; ++t) {
        const int f2 = nh * 64 + t * 16 + lm;
#pragma unroll
        for (int r = 0; r < 4; ++r) {
            const int j = mt * 16 + quad * 4 + r;
            const int n = n0 + j;
            if (n < N)
                ht1b[(size_t)n * 128 + f2] = bf1(acc[t][r] * dv[j]);
        }
    }
}

// Layer-2 gather, feature-slice-per-XCD. Block b: slice s=b&7 (16 dims),
// nodes (b>>3)*32 .. +31. Wave = 4 nodes x 16 lanes; per node 8 lane-pairs
// = 8 concurrent edge slots, each pair reads the node's 32B slice (2 x
// uint4). Reduce via shfl_xor(2,4,8); relu+bias+dinv on lanes 0-1 of each
// group; 32-node LDS run-merge (batch sorted) -> ~1-2 atomic runs/block
// of 16 scalar adds into gsum[g*128 + s*16 + d].
__global__ __launch_bounds__(512) void k_gatslice(
        const int* __restrict__ rowptr, const int* __restrict__ col,
        const unsigned short* __restrict__ ht1b,
        const float* __restrict__ dinv, const float* __restrict__ b2,
        const int* __restrict__ batch, float* __restrict__ gsum, int N) {
    __shared__ float h2s[32][16];
    __shared__ int bats[32];
    const int s = blockIdx.x & 7;          // feature slice -> XCD (round-robin)
    const int nb = blockIdx.x >> 3;
    const int tid = threadIdx.x;
    const int wave = tid >> 6, lane = tid & 63;
    const int grp = lane >> 4;             // 4 node-groups per wave
    const int gl = lane & 15;
    const int pair = gl >> 1, half = gl & 1;
    const int nl = wave * 4 + grp;         // node-local 0..31
    const int n = nb * 32 + nl;
    const unsigned short* hb = ht1b + s * 16 + half * 8;  // this lane's 16B
    float a[8] = {0.f, 0.f, 0.f, 0.f, 0.f, 0.f, 0.f, 0.f};
    if (n < N) {
        const int r0 = rowptr[n], r1 = rowptr[n + 1];
        for (int j = r0 + pair; j < r1; j += 8)
            bf8acc(*(const uint4*)(hb + (size_t)col[j] * 128), a);
        if (pair == 0)  // self loop (counted once: pre-reduce, pair 0)
            bf8acc(*(const uint4*)(hb + (size_t)n * 128), a);
    }
#pragma unroll
    for (int i = 0; i < 8; ++i) {          // reduce across the 8 pairs
        a[i] += __shfl_xor(a[i], 2);
        a[i] += __shfl_xor(a[i], 4);
        a[i] += __shfl_xor(a[i], 8);
    }
    if (pair == 0) {                       // lanes gl=0 (half 0), gl=1 (half 1)
        if (n < N) {
            const float d = dinv[n];
            const float4 bb0 = *(const float4*)(b2 + s * 16 + half * 8);
            const float4 bb1 = *(const float4*)(b2 + s * 16 + half * 8 + 4);
            const float4 v0 = make_float4(fmaxf(a[0] * d + bb0.x, 0.f),
                                          fmaxf(a[1] * d + bb0.y, 0.f),
                                          fmaxf(a[2] * d + bb0.z, 0.f),
                                          fmaxf(a[3] * d + bb0.w, 0.f));
            const float4 v1 = make_float4(fmaxf(a[4] * d + bb1.x, 0.f),
                                          fmaxf(a[5] * d + bb1.y, 0.f),
                                          fmaxf(a[6] * d + bb1.z, 0.f),
                                          fmaxf(a[7] * d + bb1.w, 0.f));
            *(float4*)&h2s[nl][half * 8] = v0;
            *(float4*)&h2s[nl][half * 8 + 4] = v1;
            if (half == 0) bats[nl] = batch[n];
        } else {
            *(float4*)&h2s[nl][half * 8] = make_float4(0.f, 0.f, 0.f, 0.f);
            *(float4*)&h2s[nl][half * 8 + 4] = make_float4(0.f, 0.f, 0.f, 0.f);
            if (half == 0) bats[nl] = -1;
        }
    }
    __syncthreads();
    if (tid < 16) {                        // dim tid of this slice
        int bprev = bats[0];
        float acc = h2s[0][tid];
#pragma unroll 4
        for (int v = 1; v < 32; ++v) {
            const int bw = bats[v];        // wave-uniform branch (LDS scalar)
            const float rv = h2s[v][tid];
            if (bw == bprev) {
                acc += rv;
            } else {
                if (bprev >= 0)
                    unsafeAtomicAdd(gsum + (size_t)bprev * 128 + s * 16 + tid, acc);
                bprev = bw; acc = rv;
            }
        }
        if (bprev >= 0)
            unsafeAtomicAdd(gsum + (size_t)bprev * 128 + s * 16 + tid, acc);
    }
}

__global__ __launch_bounds__(128) void k_head(
        const float* __restrict__ gsum, const int* __restrict__ gptr,
        const float* __restrict__ Wlab, const float* __restrict__ blab,
        const float* __restrict__ Wd1, const float* __restrict__ bd1,
        const float* __restrict__ Wd2, const float* __restrict__ bd2,
        float* __restrict__ out, int G) {
    __shared__ float sp[128];
    __shared__ float red[128];
    __shared__ float hd[64];
    const int g = blockIdx.x, t = threadIdx.x;
    const float cnt = (float)(gptr[g + 1] - gptr[g]);
    const float invc = 1.f / fmaxf(cnt, 1.f);
    const float pooled = gsum[g * 128 + t] * invc;
    sp[t] = pooled;
    red[t] = pooled * Wlab[t];
    __syncthreads();
    for (int off = 64; off > 0; off >>= 1) {
        if (t < off) red[t] += red[t + off];
        __syncthreads();
    }
    if (t == 0) {
        float z = red[0] + blab[0];
        out[g] = 1.f / (1.f + expf(-z));
    }
    if (t < 64) {
        float s = bd1[t];
        for (int f = 0; f < 128; ++f) s += sp[f] * Wd1[f * 64 + t];
        hd[t] = fmaxf(s, 0.f);
    }
    __syncthreads();
    if (t < 2) {
        float s = bd2[t];
        for (int j = 0; j < 64; ++j) s += hd[j] * Wd2[j * 2 + t];
        out[G + g * 2 + t] = s;
    }
}

extern "C" void kernel_launch(void* const* d_in, const int* in_sizes, int n_in,
                              void* d_out, int out_size, void* d_ws, size_t ws_size,
                              hipStream_t stream) {
    const float* x     = (const float*)d_in[0];
    const int*   ei    = (const int*)d_in[1];   // [2,E]: ei[e]=src, ei[E+e]=dst
    const int*   batch = (const int*)d_in[2];
    const float* W1    = (const float*)d_in[3];
    const float* b1    = (const float*)d_in[4];
    const float* W2    = (const float*)d_in[5];
    const float* b2    = (const float*)d_in[6];
    const float* Wlab  = (const float*)d_in[7];
    const float* blab  = (const float*)d_in[8];
    const float* Wd1   = (const float*)d_in[9];
    const float* bd1   = (const float*)d_in[10];
    const float* Wd2   = (const float*)d_in[11];
    const float* bd2   = (const float*)d_in[12];
    float* out = (float*)d_out;

    const int N = in_sizes[0] / 16;
    const int E = in_sizes[1] / 2;
    const int G = out_size / 3;
    const int NB = (N + 255) >> 8;             // node buckets of 256

    char* p = (char*)d_ws;
    auto carve = [&](size_t bytes) {
        void* r = (void*)p;
        p += (bytes + 255) & ~(size_t)255;
        return r;
    };
    int*      bcnt   = (int*)     carve(256 * 4);
    unsigned* col1   = (unsigned*)carve((size_t)NB * BCAP * 4);
    int*      col    = (int*)     carve((size_t)E * 4);
    int*      rowptr = (int*)     carve((size_t)(N + 1) * 4);
    int*      gptr   = (int*)     carve((size_t)(G + 1) * 4);
    float*    dinv   = (float*)   carve((size_t)N * 4);
    unsigned short* xsb  = (unsigned short*)carve((size_t)N * 16 * 2);
    unsigned short* W2bf = (unsigned short*)carve(128 * 128 * 2);
    unsigned short* ht1b = (unsigned short*)carve((size_t)N * 128 * 2);
    float*    gsum   = (float*)   carve((size_t)G * 128 * 4);

    const int FB = 256;                        // blocks for bfill
    const int chunk = (E + FB - 1) / FB;

    hipMemsetAsync(bcnt, 0, 256 * 4, stream);
    k_bfill  <<<FB, 256, 0, stream>>>(ei, bcnt, col1, batch, gptr, gsum, W2,
                                      W2bf, E, chunk, NB, N, G);
    k_bsort  <<<NB, 256, 0, stream>>>(col1, bcnt, col, rowptr, dinv, x, xsb,
                                      N, E, NB);
    k_l12g   <<<(N + 63) / 64, 512, 0, stream>>>(rowptr, col, xsb, dinv,
                                                 W1, b1, W2bf, ht1b, N);
    k_gatslice<<<((N + 31) / 32) * 8, 512, 0, stream>>>(rowptr, col, ht1b,
                                                        dinv, b2, batch,
                                                        gsum, N);
    k_head   <<<G, 128, 0, stream>>>(gsum, gptr, Wlab, blab, Wd1, bd1, Wd2,
                                     bd2, out, G);
}

// Round 6
// 236.953 us; speedup vs baseline: 1.2358x; 1.2358x over previous
//
#include <hip/hip_runtime.h>
#include <math.h>

// GCN forward, CSR-gather; bf16 xs/W2/ht1; MFMA layer-2 dense; block-
// aggregated pooling. CSR build = single-pass fixed-capacity bucket sort.
// R5: gather reverted to R0's best (uint2 2-half, 64.3us) split into two
// half-range launches (~32us each) so rocprof top-5 surfaces the true #2
// kernel (non-gather time is a stable ~165us = bfill+bsort+l12g+head,
// all individually <43.6us per R4's table). bsort moved to 128-node
// buckets x 512 threads (2x blocks, half serial work). l12g layer-1
// gather upgraded uint2->uint4 (half the VMEM instrs, 2x MLP).
// Gather-fetch model (R3/R4/R5): t ~ 32us traversal + 0.22us/MB FETCH;
// fetch is L2-capacity-driven (12.8MB table vs 4MB/XCD L2); 32B slicing
// inflates sectors 7x (R5) -- full-row gather is the right shape.
// Requires N <= 65536 (src packed in 16 bits).

#define BCAP 6144    // bucket capacity (128-node buckets, mean fill ~4.1K)

typedef __attribute__((ext_vector_type(8))) short short8;   // 8 bf16 (4 VGPRs)
typedef __attribute__((ext_vector_type(4))) float f32x4;    // MFMA accumulator

__device__ __forceinline__ void bf4acc(uint2 u, float* a) {
    a[0] += __uint_as_float(u.x << 16);
    a[1] += __uint_as_float(u.x & 0xffff0000u);
    a[2] += __uint_as_float(u.y << 16);
    a[3] += __uint_as_float(u.y & 0xffff0000u);
}

__device__ __forceinline__ void bf8acc(uint4 u, float* a) {
    a[0] += __uint_as_float(u.x << 16);
    a[1] += __uint_as_float(u.x & 0xffff0000u);
    a[2] += __uint_as_float(u.y << 16);
    a[3] += __uint_as_float(u.y & 0xffff0000u);
    a[4] += __uint_as_float(u.z << 16);
    a[5] += __uint_as_float(u.z & 0xffff0000u);
    a[6] += __uint_as_float(u.w << 16);
    a[7] += __uint_as_float(u.w & 0xffff0000u);
}

__device__ __forceinline__ unsigned short bf1(float a) {    // RNE bf16
    unsigned ua = __float_as_uint(a);
    return (unsigned short)((ua + 0x7fffu + ((ua >> 16) & 1u)) >> 16);
}

// ---- single-pass bucketed fill + prep tails (128-node buckets) ----
__global__ __launch_bounds__(256) void k_bfill(
        const int* __restrict__ ei, int* __restrict__ bcnt,
        unsigned* __restrict__ col1,
        const int* __restrict__ batch, int* __restrict__ gptr,
        float* __restrict__ gsum, const float* __restrict__ W2,
        unsigned short* __restrict__ W2bf,
        int E, int chunk, int NB, int N, int G) {
    __shared__ int bins[512];
    __shared__ int base[512];
    for (int t = threadIdx.x; t < NB; t += 256) bins[t] = 0;
    __syncthreads();
    const int e0 = blockIdx.x * chunk;
    int e1 = e0 + chunk; if (e1 > E) e1 = E;
    for (int j = e0 + (int)threadIdx.x; j < e1; j += 256)
        atomicAdd(&bins[ei[E + j] >> 7], 1);
    __syncthreads();
    for (int t = threadIdx.x; t < NB; t += 256) {
        base[t] = bins[t] ? atomicAdd(&bcnt[t], bins[t]) : 0;
        bins[t] = 0;
    }
    __syncthreads();
    for (int j = e0 + (int)threadIdx.x; j < e1; j += 256) {
        int d = ei[E + j];              // L2-warm (read in hist pass)
        int s = ei[j];
        int b = d >> 7;
        int pos = base[b] + atomicAdd(&bins[b], 1);
        if (pos < BCAP)
            col1[(size_t)b * BCAP + pos] = ((unsigned)(d & 127) << 16) | (unsigned)s;
    }

    // distributed prep tails
    const int gid = blockIdx.x * 256 + threadIdx.x;
    const int gsz = gridDim.x * 256;
    for (int i = gid; i < G * 32; i += gsz)        // gsum = 0 (float4)
        ((float4*)gsum)[i] = make_float4(0.f, 0.f, 0.f, 0.f);
    for (int i = gid; i < 16384; i += gsz) {       // W2bf[f2][f1] = bf16(W2[f1][f2])
        const int f2 = i >> 7, f1 = i & 127;
        W2bf[i] = bf1(W2[f1 * 128 + f2]);
    }
    for (int g = gid; g <= G; g += gsz) {          // gptr = lower_bound(batch,g)
        int lo = 0, hi = N;
        while (lo < hi) {
            int mid = (lo + hi) >> 1;
            if (batch[mid] < g) lo = mid + 1; else hi = mid;
        }
        gptr[g] = lo;
    }
}

// ---- per-bucket LDS sort -> exact CSR + dinv + xsb (self-scans bcnt) ----
// 128-node buckets, 512 threads: 2x grid parallelism, half the per-block
// serial work vs the 256-node/256-thread version.
__global__ __launch_bounds__(512) void k_bsort(const unsigned* __restrict__ col1,
                                               const int* __restrict__ bcnt,
                                               int* __restrict__ col,
                                               int* __restrict__ rowptr,
                                               float* __restrict__ dinv,
                                               const float* __restrict__ x,
                                               unsigned short* __restrict__ xsb,
                                               int N, int E, int NB) {
    __shared__ unsigned ec[BCAP];
    __shared__ int bins[512];
    __shared__ int sc[128], cur[128];
    __shared__ float dvb[128];
    const int b = blockIdx.x, t = threadIdx.x;

    // bucket-offset scan (NB<=512 ints, L2-hot): s0 = sum_{i<b} bcnt[i]
    bins[t] = (t < NB) ? bcnt[t] : 0;
    __syncthreads();
    for (int off = 1; off < 512; off <<= 1) {
        int add = (t >= off) ? bins[t - off] : 0;
        __syncthreads();
        bins[t] += add;
        __syncthreads();
    }
    const int s0 = (b == 0) ? 0 : bins[b - 1];
    int cnt = bcnt[b];
    if (cnt > BCAP) cnt = BCAP;        // safety clamp (never hit for this E,N)
    if (t < 128) cur[t] = 0;
    __syncthreads();

    for (int i = t; i < cnt; i += 512) ec[i] = col1[(size_t)b * BCAP + i];
    __syncthreads();
    for (int i = t; i < cnt; i += 512) atomicAdd(&cur[ec[i] >> 16], 1);
    __syncthreads();
    const int v = (t < 128) ? cur[t] : 0;   // this node's edge count
    if (t < 128) sc[t] = v;
    __syncthreads();
    for (int off = 1; off < 128; off <<= 1) {
        int add = (t >= off && t < 128) ? sc[t - off] : 0;
        __syncthreads();
        if (t < 128) sc[t] += add;
        __syncthreads();
    }
    const int ex = (t < 128) ? (sc[t] - v) : 0;
    __syncthreads();
    const int n0 = b * 128;
    if (t < 128) {
        sc[t] = ex;          // exclusive local offsets
        cur[t] = 0;          // reuse as per-node cursor
        const float dv = rsqrtf((float)(v + 1));
        dvb[t] = dv;
        if (n0 + t < N) {
            rowptr[n0 + t] = s0 + ex;
            dinv[n0 + t] = dv;
        }
    }
    if (b == 0 && t == 0) rowptr[N] = E;
    __syncthreads();
    for (int i = t; i < cnt; i += 512) {
        unsigned e = ec[i];
        int dl = e >> 16;
        int p = sc[dl] + atomicAdd(&cur[dl], 1);
        col[s0 + p] = (int)(e & 0xffffu);
    }
    // xsb = bf16(x * dinv) for this bucket's nodes (coalesced)
    int nn = N - n0; if (nn > 128) nn = 128;
    const int lim = nn * 16;
    for (int i = t; i < lim; i += 512) {
        float vx = x[(size_t)n0 * 16 + i] * dvb[i >> 4];
        xsb[(size_t)n0 * 16 + i] = bf1(vx);
    }
}

// ---- FUSED gat16 + l12 (MFMA): 64 nodes/block, 512 threads (8 waves),
//      ~57 KB LDS -> 2 blocks/CU. Layer-1 gather: uint4 lane-loads
//      (4 edge slots x 2 half-lanes per node).
__global__ __launch_bounds__(512, 4) void k_l12g(
        const int* __restrict__ rowptr, const int* __restrict__ col,
        const unsigned short* __restrict__ xsb,
        const float* __restrict__ dinv,
        const float* __restrict__ W1, const float* __restrict__ b1,
        const unsigned short* __restrict__ W2bf,   // [f2][f1] bf16
        unsigned short* __restrict__ ht1b, int N) {
    __shared__ __align__(16) unsigned short W2s[128 * 136];  // [f2][f1] padded
    __shared__ __align__(16) unsigned short h1b[64 * 136];   // [node][f1] padded
    __shared__ __align__(16) float arow[64 * 16];
    __shared__ float dv[64];
    const int tid = threadIdx.x;
    const int n0 = blockIdx.x * 64;
    const int w = tid >> 6, lane = tid & 63;

    // stage W2^T (bf16): 128 rows x 16 uint4 segments
    for (int i = tid; i < 2048; i += 512) {
        const int f2 = i >> 4, seg = i & 15;
        *(uint4*)&W2s[f2 * 136 + seg * 8] = ((const uint4*)W2bf)[i];
    }
    if (tid < 64) dv[tid] = (n0 + tid < N) ? dinv[n0 + tid] : 0.f;

    // gather: 8 lanes/node = 4 edge slots x 2 half-lanes (uint4 = 16B each)
    {
        const int nd = lane >> 3, sub = lane & 7;
        const int slot = sub >> 1, qq = sub & 1;
        const int j = w * 8 + nd;
        const int n = n0 + j;
        float a[8] = {0.f, 0.f, 0.f, 0.f, 0.f, 0.f, 0.f, 0.f};
        if (n < N) {
            const int r1 = rowptr[n + 1];
            for (int e = rowptr[n] + slot; e < r1; e += 4)
                bf8acc(*(const uint4*)(xsb + (size_t)col[e] * 16 + qq * 8), a);
        }
#pragma unroll
        for (int i = 0; i < 8; ++i) {      // reduce across the 4 slots
            a[i] += __shfl_xor(a[i], 2);
            a[i] += __shfl_xor(a[i], 4);
        }
        if (slot == 0) {
            if (n < N) {   // self loop
                bf8acc(*(const uint4*)(xsb + (size_t)n * 16 + qq * 8), a);
                *(float4*)&arow[j * 16 + qq * 8] =
                    make_float4(a[0], a[1], a[2], a[3]);
                *(float4*)&arow[j * 16 + qq * 8 + 4] =
                    make_float4(a[4], a[5], a[6], a[7]);
            } else {
                *(float4*)&arow[j * 16 + qq * 8] = make_float4(0.f, 0.f, 0.f, 0.f);
                *(float4*)&arow[j * 16 + qq * 8 + 4] = make_float4(0.f, 0.f, 0.f, 0.f);
            }
        }
    }
    const int f = tid & 127, jg = tid >> 7;
    float w1r[16];
#pragma unroll
    for (int k = 0; k < 16; ++k) w1r[k] = W1[k * 128 + f];
    const float bias = b1[f];
    __syncthreads();

    // phase 1: h1 (bf16) into A-layout LDS
#pragma unroll 4
    for (int j = jg * 16; j < jg * 16 + 16; ++j) {
        float s = 0.f;
#pragma unroll
        for (int k = 0; k < 16; ++k) s += arow[j * 16 + k] * w1r[k];
        h1b[j * 136 + f] = bf1(fmaxf(dv[j] * s + bias, 0.f));
    }
    __syncthreads();

    // phase 2: MFMA, D[64x128] = h1[64x128] @ W2[128x128]
    const int mt = w & 3, nh = w >> 2;
    const int lm = lane & 15, quad = lane >> 4;
    f32x4 acc[4];
#pragma unroll
    for (int t = 0; t < 4; ++t) acc[t] = (f32x4){0.f, 0.f, 0.f, 0.f};
#pragma unroll
    for (int kb = 0; kb < 4; ++kb) {
        const short8 af = *(const short8*)&h1b[(mt * 16 + lm) * 136 + kb * 32 + quad * 8];
#pragma unroll
        for (int t = 0; t < 4; ++t) {
            const short8 bfv = *(const short8*)&W2s[(nh * 64 + t * 16 + lm) * 136 + kb * 32 + quad * 8];
            acc[t] = __builtin_amdgcn_mfma_f32_16x16x32_bf16(af, bfv, acc[t], 0, 0, 0);
        }
    }
    // epilogue: *dinv, pack bf16, store
#pragma unroll
    for (int t = 0; t < 4; ++t) {
        const int f2 = nh * 64 + t * 16 + lm;
#pragma unroll
        for (int r = 0; r < 4; ++r) {
            const int j = mt * 16 + quad * 4 + r;
            const int n = n0 + j;
            if (n < N)
                ht1b[(size_t)n * 128 + f2] = bf1(acc[t][r] * dv[j]);
        }
    }
}

// Wave/node gather (R0-best structure: 2 halves x 32 lanes x uint2, 4x
// unroll -> 8 rows in flight), then 8-node LDS run-merge (batch sorted)
// -> ~1 atomic set/block. nbase: half-range launch (diagnostic split so
// rocprof top-5 surfaces the #2 kernel).
__global__ __launch_bounds__(512) void k_gat128pool(
        const int* __restrict__ rowptr, const int* __restrict__ col,
        const unsigned short* __restrict__ ht1b,
        const float* __restrict__ dinv, const float* __restrict__ b2,
        const int* __restrict__ batch, float* __restrict__ gsum,
        int N, int nbase) {
    __shared__ __align__(16) float h2s[8][128];
    __shared__ int bats[8];
    const int wave = threadIdx.x >> 6, lane = threadIdx.x & 63;
    const int half = lane >> 5, q = lane & 31;
    const int n = nbase + blockIdx.x * 8 + wave;
    float a[4] = {0.f, 0.f, 0.f, 0.f};
    if (n < N) {
        const int r0 = rowptr[n], r1 = rowptr[n + 1];
        int j = r0 + half;
        while (j + 6 < r1) {
            int s0 = col[j], s1 = col[j + 2], s2 = col[j + 4], s3 = col[j + 6];
            uint2 u0 = *(const uint2*)(ht1b + (size_t)s0 * 128 + q * 4);
            uint2 u1 = *(const uint2*)(ht1b + (size_t)s1 * 128 + q * 4);
            uint2 u2 = *(const uint2*)(ht1b + (size_t)s2 * 128 + q * 4);
            uint2 u3 = *(const uint2*)(ht1b + (size_t)s3 * 128 + q * 4);
            bf4acc(u0, a); bf4acc(u1, a); bf4acc(u2, a); bf4acc(u3, a);
            j += 8;
        }
        while (j < r1) {
            bf4acc(*(const uint2*)(ht1b + (size_t)col[j] * 128 + q * 4), a);
            j += 2;
        }
        if (half == 0)  // self loop
            bf4acc(*(const uint2*)(ht1b + (size_t)n * 128 + q * 4), a);
    }
#pragma unroll
    for (int i = 0; i < 4; ++i) a[i] += __shfl_xor(a[i], 32);
    if (half == 0) {
        if (n < N) {
            const float d = dinv[n];
            const float4 bb = *(const float4*)(b2 + q * 4);
            h2s[wave][q * 4 + 0] = fmaxf(a[0] * d + bb.x, 0.f);
            h2s[wave][q * 4 + 1] = fmaxf(a[1] * d + bb.y, 0.f);
            h2s[wave][q * 4 + 2] = fmaxf(a[2] * d + bb.z, 0.f);
            h2s[wave][q * 4 + 3] = fmaxf(a[3] * d + bb.w, 0.f);
            if (q == 0) bats[wave] = batch[n];
        } else {
            h2s[wave][q * 4 + 0] = 0.f; h2s[wave][q * 4 + 1] = 0.f;
            h2s[wave][q * 4 + 2] = 0.f; h2s[wave][q * 4 + 3] = 0.f;
            if (q == 0) bats[wave] = -1;
        }
    }
    __syncthreads();
    if (threadIdx.x < 32) {
        const int qq = threadIdx.x;
        int bprev = bats[0];
        float4 acc4 = *(const float4*)&h2s[0][qq * 4];
#pragma unroll
        for (int wv = 1; wv < 8; ++wv) {
            const int bw = bats[wv];   // wave-uniform branch (LDS scalar)
            const float4 rv = *(const float4*)&h2s[wv][qq * 4];
            if (bw == bprev) {
                acc4.x += rv.x; acc4.y += rv.y; acc4.z += rv.z; acc4.w += rv.w;
            } else {
                if (bprev >= 0) {
                    float* gs = gsum + (size_t)bprev * 128 + qq * 4;
                    unsafeAtomicAdd(gs + 0, acc4.x); unsafeAtomicAdd(gs + 1, acc4.y);
                    unsafeAtomicAdd(gs + 2, acc4.z); unsafeAtomicAdd(gs + 3, acc4.w);
                }
                bprev = bw; acc4 = rv;
            }
        }
        if (bprev >= 0) {
            float* gs = gsum + (size_t)bprev * 128 + qq * 4;
            unsafeAtomicAdd(gs + 0, acc4.x); unsafeAtomicAdd(gs + 1, acc4.y);
            unsafeAtomicAdd(gs + 2, acc4.z); unsafeAtomicAdd(gs + 3, acc4.w);
        }
    }
}

__global__ __launch_bounds__(128) void k_head(
        const float* __restrict__ gsum, const int* __restrict__ gptr,
        const float* __restrict__ Wlab, const float* __restrict__ blab,
        const float* __restrict__ Wd1, const float* __restrict__ bd1,
        const float* __restrict__ Wd2, const float* __restrict__ bd2,
        float* __restrict__ out, int G) {
    __shared__ float sp[128];
    __shared__ float red[128];
    __shared__ float hd[64];
    const int g = blockIdx.x, t = threadIdx.x;
    const float cnt = (float)(gptr[g + 1] - gptr[g]);
    const float invc = 1.f / fmaxf(cnt, 1.f);
    const float pooled = gsum[g * 128 + t] * invc;
    sp[t] = pooled;
    red[t] = pooled * Wlab[t];
    __syncthreads();
    for (int off = 64; off > 0; off >>= 1) {
        if (t < off) red[t] += red[t + off];
        __syncthreads();
    }
    if (t == 0) {
        float z = red[0] + blab[0];
        out[g] = 1.f / (1.f + expf(-z));
    }
    if (t < 64) {
        float s = bd1[t];
        for (int f = 0; f < 128; ++f) s += sp[f] * Wd1[f * 64 + t];
        hd[t] = fmaxf(s, 0.f);
    }
    __syncthreads();
    if (t < 2) {
        float s = bd2[t];
        for (int j = 0; j < 64; ++j) s += hd[j] * Wd2[j * 2 + t];
        out[G + g * 2 + t] = s;
    }
}

extern "C" void kernel_launch(void* const* d_in, const int* in_sizes, int n_in,
                              void* d_out, int out_size, void* d_ws, size_t ws_size,
                              hipStream_t stream) {
    const float* x     = (const float*)d_in[0];
    const int*   ei    = (const int*)d_in[1];   // [2,E]: ei[e]=src, ei[E+e]=dst
    const int*   batch = (const int*)d_in[2];
    const float* W1    = (const float*)d_in[3];
    const float* b1    = (const float*)d_in[4];
    const float* W2    = (const float*)d_in[5];
    const float* b2    = (const float*)d_in[6];
    const float* Wlab  = (const float*)d_in[7];
    const float* blab  = (const float*)d_in[8];
    const float* Wd1   = (const float*)d_in[9];
    const float* bd1   = (const float*)d_in[10];
    const float* Wd2   = (const float*)d_in[11];
    const float* bd2   = (const float*)d_in[12];
    float* out = (float*)d_out;

    const int N = in_sizes[0] / 16;
    const int E = in_sizes[1] / 2;
    const int G = out_size / 3;
    const int NB = (N + 127) >> 7;             // node buckets of 128

    char* p = (char*)d_ws;
    auto carve = [&](size_t bytes) {
        void* r = (void*)p;
        p += (bytes + 255) & ~(size_t)255;
        return r;
    };
    int*      bcnt   = (int*)     carve(512 * 4);
    unsigned* col1   = (unsigned*)carve((size_t)NB * BCAP * 4);
    int*      col    = (int*)     carve((size_t)E * 4);
    int*      rowptr = (int*)     carve((size_t)(N + 1) * 4);
    int*      gptr   = (int*)     carve((size_t)(G + 1) * 4);
    float*    dinv   = (float*)   carve((size_t)N * 4);
    unsigned short* xsb  = (unsigned short*)carve((size_t)N * 16 * 2);
    unsigned short* W2bf = (unsigned short*)carve(128 * 128 * 2);
    unsigned short* ht1b = (unsigned short*)carve((size_t)N * 128 * 2);
    float*    gsum   = (float*)   carve((size_t)G * 128 * 4);

    const int FB = 256;                        // blocks for bfill
    const int chunk = (E + FB - 1) / FB;

    // half-range split for the layer-2 gather (8-aligned)
    const int NA = ((N / 2) + 7) & ~7;
    const int blocksA = NA / 8;
    const int blocksB = (N - NA + 7) / 8;

    hipMemsetAsync(bcnt, 0, 512 * 4, stream);
    k_bfill  <<<FB, 256, 0, stream>>>(ei, bcnt, col1, batch, gptr, gsum, W2,
                                      W2bf, E, chunk, NB, N, G);
    k_bsort  <<<NB, 512, 0, stream>>>(col1, bcnt, col, rowptr, dinv, x, xsb,
                                      N, E, NB);
    k_l12g   <<<(N + 63) / 64, 512, 0, stream>>>(rowptr, col, xsb, dinv,
                                                 W1, b1, W2bf, ht1b, N);
    k_gat128pool<<<blocksA, 512, 0, stream>>>(rowptr, col, ht1b, dinv, b2,
                                              batch, gsum, N, 0);
    k_gat128pool<<<blocksB, 512, 0, stream>>>(rowptr, col, ht1b, dinv, b2,
                                              batch, gsum, N, NA);
    k_head   <<<G, 128, 0, stream>>>(gsum, gptr, Wlab, blab, Wd1, bd1, Wd2,
                                     bd2, out, G);
}

// Round 7
// 222.912 us; speedup vs baseline: 1.3137x; 1.0630x over previous
//
#include <hip/hip_runtime.h>
#include <math.h>

// GCN forward, CSR-gather; bf16 xs/W2/ht1; MFMA layer-2 dense; block-
// aggregated pooling. CSR build = single-pass fixed-capacity bucket sort.
// R7: reverted R6's regressions (bsort back to 256-node buckets/256thr,
// l12g back to uint2 gather, single gather launch) -- R6 was +7us net.
// NEW: k_bfill stages a 4096-edge tile in LDS, block-local counting sort
// by bucket, then COALESCED run copy-out (runs ~21 edges = 84B contiguous)
// -- kills the 4B-per-line scatter write amplification on col1 (est.
// 50-100MB writeback -> ~10MB). Known budget (R6): harness poison fill
// 45us (WRITE 268MB @ 6TB/s, not controllable), gather 64us (L2-miss-path
// service on 149MB, near floor: compulsory 8-XCD fetch = 102MB),
// remainder ~120us across bfill/bsort/l12g/head/launch gaps.
// Requires N <= 65536 (src packed in 16 bits, bucket fits 8 bits).

#define BCAP 12288   // bucket capacity (mean fill ~8.2K, 45 sigma headroom)
#define TILE 4096    // bfill edges per block (LDS-staged)

typedef __attribute__((ext_vector_type(8))) short short8;   // 8 bf16 (4 VGPRs)
typedef __attribute__((ext_vector_type(4))) float f32x4;    // MFMA accumulator

__device__ __forceinline__ void bf4acc(uint2 u, float* a) {
    a[0] += __uint_as_float(u.x << 16);
    a[1] += __uint_as_float(u.x & 0xffff0000u);
    a[2] += __uint_as_float(u.y << 16);
    a[3] += __uint_as_float(u.y & 0xffff0000u);
}

__device__ __forceinline__ unsigned short bf1(float a) {    // RNE bf16
    unsigned ua = __float_as_uint(a);
    return (unsigned short)((ua + 0x7fffu + ((ua >> 16) & 1u)) >> 16);
}

// ---- LDS-staged bucketed fill: tile -> local counting sort -> coalesced
//      per-bucket run copy-out (one global atomic per (block,bucket)) ----
__global__ __launch_bounds__(256) void k_bfill(
        const int* __restrict__ ei, int* __restrict__ bcnt,
        unsigned* __restrict__ col1,
        const int* __restrict__ batch, int* __restrict__ gptr,
        float* __restrict__ gsum, const float* __restrict__ W2,
        unsigned short* __restrict__ W2bf,
        int E, int NB, int N, int G) {
    __shared__ unsigned ev[TILE];      // (b<<24)|(dstLocal<<16)|src
    __shared__ unsigned es[TILE];      // bucket-sorted
    __shared__ int bins[256], scn[256], cur[256], gbase[256];
    const int t = threadIdx.x;
    const int e0 = blockIdx.x * TILE;
    int cnt = E - e0; if (cnt > TILE) cnt = TILE;

    bins[t] = 0;
    __syncthreads();
    for (int i = t; i < cnt; i += 256) {        // stage + histogram
        const int d = ei[E + e0 + i];
        const int s = ei[e0 + i];
        const unsigned b = (unsigned)d >> 8;    // NB <= 256 -> fits 8 bits
        ev[i] = (b << 24) | ((unsigned)(d & 255) << 16) | (unsigned)s;
        atomicAdd(&bins[b], 1);
    }
    __syncthreads();
    const int v = bins[t];
    scn[t] = v;
    __syncthreads();
    for (int off = 1; off < 256; off <<= 1) {   // inclusive scan
        int add = (t >= off) ? scn[t - off] : 0;
        __syncthreads();
        scn[t] += add;
        __syncthreads();
    }
    const int ex = scn[t] - v;
    __syncthreads();
    scn[t] = ex;                                // exclusive local offsets
    cur[t] = 0;
    gbase[t] = v ? atomicAdd(&bcnt[t], v) : 0;  // reserve global run
    __syncthreads();
    for (int i = t; i < cnt; i += 256) {        // scatter within LDS
        const unsigned e = ev[i];
        const int b = e >> 24;
        const int p = scn[b] + atomicAdd(&cur[b], 1);
        es[p] = e;
    }
    __syncthreads();
    for (int i = t; i < cnt; i += 256) {        // coalesced copy-out
        const unsigned e = es[i];
        const int b = e >> 24;
        const int pos = gbase[b] + (i - scn[b]);
        if (pos < BCAP)
            col1[(size_t)b * BCAP + pos] = e & 0xffffffu;
    }

    // distributed prep tails
    const int gid = blockIdx.x * 256 + t;
    const int gsz = gridDim.x * 256;
    for (int i = gid; i < G * 32; i += gsz)        // gsum = 0 (float4)
        ((float4*)gsum)[i] = make_float4(0.f, 0.f, 0.f, 0.f);
    for (int i = gid; i < 16384; i += gsz) {       // W2bf[f2][f1] = bf16(W2[f1][f2])
        const int f2 = i >> 7, f1 = i & 127;
        W2bf[i] = bf1(W2[f1 * 128 + f2]);
    }
    for (int g = gid; g <= G; g += gsz) {          // gptr = lower_bound(batch,g)
        int lo = 0, hi = N;
        while (lo < hi) {
            int mid = (lo + hi) >> 1;
            if (batch[mid] < g) lo = mid + 1; else hi = mid;
        }
        gptr[g] = lo;
    }
}

// ---- per-bucket LDS sort -> exact CSR + dinv + xsb (self-scans bcnt) ----
__global__ __launch_bounds__(256) void k_bsort(const unsigned* __restrict__ col1,
                                               const int* __restrict__ bcnt,
                                               int* __restrict__ col,
                                               int* __restrict__ rowptr,
                                               float* __restrict__ dinv,
                                               const float* __restrict__ x,
                                               unsigned short* __restrict__ xsb,
                                               int N, int E, int NB) {
    __shared__ unsigned ec[BCAP];
    __shared__ int bins[256], sc[256];
    __shared__ float dvb[256];
    const int b = blockIdx.x, t = threadIdx.x;

    // bucket-offset scan (196 ints, L2-hot): s0 = sum_{i<b} bcnt[i]
    {
        int v = (t < NB) ? bcnt[t] : 0;
        bins[t] = v;
        __syncthreads();
        for (int off = 1; off < 256; off <<= 1) {
            int add = (t >= off) ? bins[t - off] : 0;
            __syncthreads();
            bins[t] += add;
            __syncthreads();
        }
    }
    const int s0 = (b == 0) ? 0 : bins[b - 1];
    int cnt = bcnt[b];
    if (cnt > BCAP) cnt = BCAP;        // safety clamp (never hit for this E,N)
    __syncthreads();

    for (int i = t; i < cnt; i += 256) ec[i] = col1[(size_t)b * BCAP + i];
    bins[t] = 0;
    __syncthreads();
    for (int i = t; i < cnt; i += 256) atomicAdd(&bins[ec[i] >> 16], 1);
    __syncthreads();
    const int v = bins[t];
    sc[t] = v;
    __syncthreads();
    for (int off = 1; off < 256; off <<= 1) {
        int add = (t >= off) ? sc[t - off] : 0;
        __syncthreads();
        sc[t] += add;
        __syncthreads();
    }
    const int ex = sc[t] - v;
    __syncthreads();
    sc[t] = ex;          // exclusive local offsets
    bins[t] = 0;         // reuse as per-node cursor
    const float dv = rsqrtf((float)(v + 1));
    dvb[t] = dv;
    const int n0 = b * 256;
    if (n0 + t < N) {
        rowptr[n0 + t] = s0 + ex;
        dinv[n0 + t] = dv;
    }
    if (b == 0 && t == 0) rowptr[N] = E;
    __syncthreads();
    for (int i = t; i < cnt; i += 256) {
        unsigned e = ec[i];
        int dl = e >> 16;
        int p = sc[dl] + atomicAdd(&bins[dl], 1);
        col[s0 + p] = (int)(e & 0xffffu);
    }
    // xsb = bf16(x * dinv) for this bucket's nodes (coalesced)
    int nn = N - n0; if (nn > 256) nn = 256;
    const int lim = nn * 16;
    for (int i = t; i < lim; i += 256) {
        float vx = x[(size_t)n0 * 16 + i] * dvb[i >> 4];
        xsb[(size_t)n0 * 16 + i] = bf1(vx);
    }
}

// ---- FUSED gat16 + l12 (MFMA): 64 nodes/block, 512 threads (8 waves),
//      ~57 KB LDS -> 2 blocks/CU.
__global__ __launch_bounds__(512, 4) void k_l12g(
        const int* __restrict__ rowptr, const int* __restrict__ col,
        const unsigned short* __restrict__ xsb,
        const float* __restrict__ dinv,
        const float* __restrict__ W1, const float* __restrict__ b1,
        const unsigned short* __restrict__ W2bf,   // [f2][f1] bf16
        unsigned short* __restrict__ ht1b, int N) {
    __shared__ __align__(16) unsigned short W2s[128 * 136];  // [f2][f1] padded
    __shared__ __align__(16) unsigned short h1b[64 * 136];   // [node][f1] padded
    __shared__ __align__(16) float arow[64 * 16];
    __shared__ float dv[64];
    const int tid = threadIdx.x;
    const int n0 = blockIdx.x * 64;
    const int w = tid >> 6, lane = tid & 63;

    // stage W2^T (bf16): 128 rows x 16 uint4 segments
    for (int i = tid; i < 2048; i += 512) {
        const int f2 = i >> 4, seg = i & 15;
        *(uint4*)&W2s[f2 * 136 + seg * 8] = ((const uint4*)W2bf)[i];
    }
    if (tid < 64) dv[tid] = (n0 + tid < N) ? dinv[n0 + tid] : 0.f;

    // gather: 8 lanes per node (2 edge slots x 4 quarters), 8 nodes per wave
    {
        const int nd = lane >> 3, sub = lane & 7;
        const int slot = sub >> 2, qq = sub & 3;
        const int j = w * 8 + nd;
        const int n = n0 + j;
        float a[4] = {0.f, 0.f, 0.f, 0.f};
        if (n < N) {
            const int r1 = rowptr[n + 1];
            for (int e = rowptr[n] + slot; e < r1; e += 2)
                bf4acc(*(const uint2*)(xsb + (size_t)col[e] * 16 + qq * 4), a);
        }
#pragma unroll
        for (int i = 0; i < 4; ++i) a[i] += __shfl_xor(a[i], 4);
        if (slot == 0) {
            if (n < N) {   // self loop
                bf4acc(*(const uint2*)(xsb + (size_t)n * 16 + qq * 4), a);
                *(float4*)&arow[j * 16 + qq * 4] = make_float4(a[0], a[1], a[2], a[3]);
            } else {
                *(float4*)&arow[j * 16 + qq * 4] = make_float4(0.f, 0.f, 0.f, 0.f);
            }
        }
    }
    const int f = tid & 127, jg = tid >> 7;
    float w1r[16];
#pragma unroll
    for (int k = 0; k < 16; ++k) w1r[k] = W1[k * 128 + f];
    const float bias = b1[f];
    __syncthreads();

    // phase 1: h1 (bf16) into A-layout LDS
#pragma unroll 4
    for (int j = jg * 16; j < jg * 16 + 16; ++j) {
        float s = 0.f;
#pragma unroll
        for (int k = 0; k < 16; ++k) s += arow[j * 16 + k] * w1r[k];
        h1b[j * 136 + f] = bf1(fmaxf(dv[j] * s + bias, 0.f));
    }
    __syncthreads();

    // phase 2: MFMA, D[64x128] = h1[64x128] @ W2[128x128]
    const int mt = w & 3, nh = w >> 2;
    const int lm = lane & 15, quad = lane >> 4;
    f32x4 acc[4];
#pragma unroll
    for (int t = 0; t < 4; ++t) acc[t] = (f32x4){0.f, 0.f, 0.f, 0.f};
#pragma unroll
    for (int kb = 0; kb < 4; ++kb) {
        const short8 af = *(const short8*)&h1b[(mt * 16 + lm) * 136 + kb * 32 + quad * 8];
#pragma unroll
        for (int t = 0; t < 4; ++t) {
            const short8 bfv = *(const short8*)&W2s[(nh * 64 + t * 16 + lm) * 136 + kb * 32 + quad * 8];
            acc[t] = __builtin_amdgcn_mfma_f32_16x16x32_bf16(af, bfv, acc[t], 0, 0, 0);
        }
    }
    // epilogue: *dinv, pack bf16, store
#pragma unroll
    for (int t = 0; t < 4; ++t) {
        const int f2 = nh * 64 + t * 16 + lm;
#pragma unroll
        for (int r = 0; r < 4; ++r) {
            const int j = mt * 16 + quad * 4 + r;
            const int n = n0 + j;
            if (n < N)
                ht1b[(size_t)n * 128 + f2] = bf1(acc[t][r] * dv[j]);
        }
    }
}

// Wave/node gather (2 halves x 32 lanes x uint2, 4x unroll -> 8 rows in
// flight), then 8-node LDS run-merge (batch sorted) -> ~1 atomic set/block.
__global__ __launch_bounds__(512) void k_gat128pool(
        const int* __restrict__ rowptr, const int* __restrict__ col,
        const unsigned short* __restrict__ ht1b,
        const float* __restrict__ dinv, const float* __restrict__ b2,
        const int* __restrict__ batch, float* __restrict__ gsum, int N) {
    __shared__ __align__(16) float h2s[8][128];
    __shared__ int bats[8];
    const int wave = threadIdx.x >> 6, lane = threadIdx.x & 63;
    const int half = lane >> 5, q = lane & 31;
    const int n = blockIdx.x * 8 + wave;
    float a[4] = {0.f, 0.f, 0.f, 0.f};
    if (n < N) {
        const int r0 = rowptr[n], r1 = rowptr[n + 1];
        int j = r0 + half;
        while (j + 6 < r1) {
            int s0 = col[j], s1 = col[j + 2], s2 = col[j + 4], s3 = col[j + 6];
            uint2 u0 = *(const uint2*)(ht1b + (size_t)s0 * 128 + q * 4);
            uint2 u1 = *(const uint2*)(ht1b + (size_t)s1 * 128 + q * 4);
            uint2 u2 = *(const uint2*)(ht1b + (size_t)s2 * 128 + q * 4);
            uint2 u3 = *(const uint2*)(ht1b + (size_t)s3 * 128 + q * 4);
            bf4acc(u0, a); bf4acc(u1, a); bf4acc(u2, a); bf4acc(u3, a);
            j += 8;
        }
        while (j < r1) {
            bf4acc(*(const uint2*)(ht1b + (size_t)col[j] * 128 + q * 4), a);
            j += 2;
        }
        if (half == 0)  // self loop
            bf4acc(*(const uint2*)(ht1b + (size_t)n * 128 + q * 4), a);
    }
#pragma unroll
    for (int i = 0; i < 4; ++i) a[i] += __shfl_xor(a[i], 32);
    if (half == 0) {
        if (n < N) {
            const float d = dinv[n];
            const float4 bb = *(const float4*)(b2 + q * 4);
            h2s[wave][q * 4 + 0] = fmaxf(a[0] * d + bb.x, 0.f);
            h2s[wave][q * 4 + 1] = fmaxf(a[1] * d + bb.y, 0.f);
            h2s[wave][q * 4 + 2] = fmaxf(a[2] * d + bb.z, 0.f);
            h2s[wave][q * 4 + 3] = fmaxf(a[3] * d + bb.w, 0.f);
            if (q == 0) bats[wave] = batch[n];
        } else {
            h2s[wave][q * 4 + 0] = 0.f; h2s[wave][q * 4 + 1] = 0.f;
            h2s[wave][q * 4 + 2] = 0.f; h2s[wave][q * 4 + 3] = 0.f;
            if (q == 0) bats[wave] = -1;
        }
    }
    __syncthreads();
    if (threadIdx.x < 32) {
        const int qq = threadIdx.x;
        int bprev = bats[0];
        float4 acc4 = *(const float4*)&h2s[0][qq * 4];
#pragma unroll
        for (int wv = 1; wv < 8; ++wv) {
            const int bw = bats[wv];   // wave-uniform branch (LDS scalar)
            const float4 rv = *(const float4*)&h2s[wv][qq * 4];
            if (bw == bprev) {
                acc4.x += rv.x; acc4.y += rv.y; acc4.z += rv.z; acc4.w += rv.w;
            } else {
                if (bprev >= 0) {
                    float* gs = gsum + (size_t)bprev * 128 + qq * 4;
                    unsafeAtomicAdd(gs + 0, acc4.x); unsafeAtomicAdd(gs + 1, acc4.y);
                    unsafeAtomicAdd(gs + 2, acc4.z); unsafeAtomicAdd(gs + 3, acc4.w);
                }
                bprev = bw; acc4 = rv;
            }
        }
        if (bprev >= 0) {
            float* gs = gsum + (size_t)bprev * 128 + qq * 4;
            unsafeAtomicAdd(gs + 0, acc4.x); unsafeAtomicAdd(gs + 1, acc4.y);
            unsafeAtomicAdd(gs + 2, acc4.z); unsafeAtomicAdd(gs + 3, acc4.w);
        }
    }
}

__global__ __launch_bounds__(128) void k_head(
        const float* __restrict__ gsum, const int* __restrict__ gptr,
        const float* __restrict__ Wlab, const float* __restrict__ blab,
        const float* __restrict__ Wd1, const float* __restrict__ bd1,
        const float* __restrict__ Wd2, const float* __restrict__ bd2,
        float* __restrict__ out, int G) {
    __shared__ float sp[128];
    __shared__ float red[128];
    __shared__ float hd[64];
    const int g = blockIdx.x, t = threadIdx.x;
    const float cnt = (float)(gptr[g + 1] - gptr[g]);
    const float invc = 1.f / fmaxf(cnt, 1.f);
    const float pooled = gsum[g * 128 + t] * invc;
    sp[t] = pooled;
    red[t] = pooled * Wlab[t];
    __syncthreads();
    for (int off = 64; off > 0; off >>= 1) {
        if (t < off) red[t] += red[t + off];
        __syncthreads();
    }
    if (t == 0) {
        float z = red[0] + blab[0];
        out[g] = 1.f / (1.f + expf(-z));
    }
    if (t < 64) {
        float s = bd1[t];
        for (int f = 0; f < 128; ++f) s += sp[f] * Wd1[f * 64 + t];
        hd[t] = fmaxf(s, 0.f);
    }
    __syncthreads();
    if (t < 2) {
        float s = bd2[t];
        for (int j = 0; j < 64; ++j) s += hd[j] * Wd2[j * 2 + t];
        out[G + g * 2 + t] = s;
    }
}

extern "C" void kernel_launch(void* const* d_in, const int* in_sizes, int n_in,
                              void* d_out, int out_size, void* d_ws, size_t ws_size,
                              hipStream_t stream) {
    const float* x     = (const float*)d_in[0];
    const int*   ei    = (const int*)d_in[1];   // [2,E]: ei[e]=src, ei[E+e]=dst
    const int*   batch = (const int*)d_in[2];
    const float* W1    = (const float*)d_in[3];
    const float* b1    = (const float*)d_in[4];
    const float* W2    = (const float*)d_in[5];
    const float* b2    = (const float*)d_in[6];
    const float* Wlab  = (const float*)d_in[7];
    const float* blab  = (const float*)d_in[8];
    const float* Wd1   = (const float*)d_in[9];
    const float* bd1   = (const float*)d_in[10];
    const float* Wd2   = (const float*)d_in[11];
    const float* bd2   = (const float*)d_in[12];
    float* out = (float*)d_out;

    const int N = in_sizes[0] / 16;
    const int E = in_sizes[1] / 2;
    const int G = out_size / 3;
    const int NB = (N + 255) >> 8;             // node buckets of 256

    char* p = (char*)d_ws;
    auto carve = [&](size_t bytes) {
        void* r = (void*)p;
        p += (bytes + 255) & ~(size_t)255;
        return r;
    };
    int*      bcnt   = (int*)     carve(256 * 4);
    unsigned* col1   = (unsigned*)carve((size_t)NB * BCAP * 4);
    int*      col    = (int*)     carve((size_t)E * 4);
    int*      rowptr = (int*)     carve((size_t)(N + 1) * 4);
    int*      gptr   = (int*)     carve((size_t)(G + 1) * 4);
    float*    dinv   = (float*)   carve((size_t)N * 4);
    unsigned short* xsb  = (unsigned short*)carve((size_t)N * 16 * 2);
    unsigned short* W2bf = (unsigned short*)carve(128 * 128 * 2);
    unsigned short* ht1b = (unsigned short*)carve((size_t)N * 128 * 2);
    float*    gsum   = (float*)   carve((size_t)G * 128 * 4);

    const int FB = (E + TILE - 1) / TILE;      // bfill: one LDS tile/block

    hipMemsetAsync(bcnt, 0, 256 * 4, stream);
    k_bfill  <<<FB, 256, 0, stream>>>(ei, bcnt, col1, batch, gptr, gsum, W2,
                                      W2bf, E, NB, N, G);
    k_bsort  <<<NB, 256, 0, stream>>>(col1, bcnt, col, rowptr, dinv, x, xsb,
                                      N, E, NB);
    k_l12g   <<<(N + 63) / 64, 512, 0, stream>>>(rowptr, col, xsb, dinv,
                                                 W1, b1, W2bf, ht1b, N);
    k_gat128pool<<<(N + 7) / 8, 512, 0, stream>>>(rowptr, col, ht1b, dinv, b2,
                                                  batch, gsum, N);
    k_head   <<<G, 128, 0, stream>>>(gsum, gptr, Wlab, blab, Wd1, bd1, Wd2,
                                     bd2, out, G);
}

// Round 8
// 222.128 us; speedup vs baseline: 1.3183x; 1.0035x over previous
//
#include <hip/hip_runtime.h>
#include <math.h>

// GCN forward, CSR-gather; bf16 xs/W2/ht1; MFMA layer-2 dense; block-
// aggregated pooling. CSR build = single-pass fixed-capacity bucket sort.
// R8: serial-depth cuts in the build kernels (gather+l12g untouched):
//   bfill: TILE 4096->8192, 512thr -- copy-out runs 64B->128B (full line),
//          half the reserve atomics, same per-thread staging (16 iters).
//   bsort: 256->512 threads on 256-node buckets -- the 3 passes over
//          ~8.2K edges halve serial depth (196 blocks < 256 CUs, so
//          per-block latency IS the kernel time).
//   head:  domain-head 128-iter loop split-K across all 128 threads.
// Known budget (R6/R7): gather 64.2us (fetch-bound, t ~ 32 + 0.21/MB,
// ~20us above compulsory-fetch floor; bf16->fp8 is the only further lever
// and risks absmax), harness poison fill ~45us (not controllable),
// remainder ~114us across build kernels + gaps -- this round's target.
// Requires N <= 65536 (src packed in 16 bits, bucket fits 8 bits).

#define BCAP 12288   // bucket capacity (mean fill ~8.2K, 45 sigma headroom)
#define TILE 8192    // bfill edges per block (LDS-staged, 64KB)

typedef __attribute__((ext_vector_type(8))) short short8;   // 8 bf16 (4 VGPRs)
typedef __attribute__((ext_vector_type(4))) float f32x4;    // MFMA accumulator

__device__ __forceinline__ void bf4acc(uint2 u, float* a) {
    a[0] += __uint_as_float(u.x << 16);
    a[1] += __uint_as_float(u.x & 0xffff0000u);
    a[2] += __uint_as_float(u.y << 16);
    a[3] += __uint_as_float(u.y & 0xffff0000u);
}

__device__ __forceinline__ unsigned short bf1(float a) {    // RNE bf16
    unsigned ua = __float_as_uint(a);
    return (unsigned short)((ua + 0x7fffu + ((ua >> 16) & 1u)) >> 16);
}

// ---- LDS-staged bucketed fill: 8192-edge tile -> local counting sort ->
//      coalesced per-bucket run copy-out (~32 edges = 128B per run) ----
__global__ __launch_bounds__(512) void k_bfill(
        const int* __restrict__ ei, int* __restrict__ bcnt,
        unsigned* __restrict__ col1,
        const int* __restrict__ batch, int* __restrict__ gptr,
        float* __restrict__ gsum, const float* __restrict__ W2,
        unsigned short* __restrict__ W2bf,
        int E, int NB, int N, int G) {
    __shared__ unsigned ev[TILE];      // (b<<24)|(dstLocal<<16)|src
    __shared__ unsigned es[TILE];      // bucket-sorted
    __shared__ int bins[256], scn[256], cur[256], gbase[256];
    const int t = threadIdx.x;
    const int e0 = blockIdx.x * TILE;
    int cnt = E - e0; if (cnt > TILE) cnt = TILE;

    if (t < 256) bins[t] = 0;
    __syncthreads();
    for (int i = t; i < cnt; i += 512) {        // stage + histogram
        const int d = ei[E + e0 + i];
        const int s = ei[e0 + i];
        const unsigned b = (unsigned)d >> 8;    // NB <= 256 -> fits 8 bits
        ev[i] = (b << 24) | ((unsigned)(d & 255) << 16) | (unsigned)s;
        atomicAdd(&bins[b], 1);
    }
    __syncthreads();
    int v = 0;
    if (t < 256) { v = bins[t]; scn[t] = v; }
    __syncthreads();
    for (int off = 1; off < 256; off <<= 1) {   // inclusive scan (256-wide)
        int add = (t >= off && t < 256) ? scn[t - off] : 0;
        __syncthreads();
        if (t < 256) scn[t] += add;
        __syncthreads();
    }
    int ex = 0;
    if (t < 256) ex = scn[t] - v;
    __syncthreads();
    if (t < 256) {
        scn[t] = ex;                            // exclusive local offsets
        cur[t] = 0;
        gbase[t] = v ? atomicAdd(&bcnt[t], v) : 0;  // reserve global run
    }
    __syncthreads();
    for (int i = t; i < cnt; i += 512) {        // scatter within LDS
        const unsigned e = ev[i];
        const int b = e >> 24;
        const int p = scn[b] + atomicAdd(&cur[b], 1);
        es[p] = e;
    }
    __syncthreads();
    for (int i = t; i < cnt; i += 512) {        // coalesced copy-out
        const unsigned e = es[i];
        const int b = e >> 24;
        const int pos = gbase[b] + (i - scn[b]);
        if (pos < BCAP)
            col1[(size_t)b * BCAP + pos] = e & 0xffffffu;
    }

    // distributed prep tails
    const int gid = blockIdx.x * 512 + t;
    const int gsz = gridDim.x * 512;
    for (int i = gid; i < G * 32; i += gsz)        // gsum = 0 (float4)
        ((float4*)gsum)[i] = make_float4(0.f, 0.f, 0.f, 0.f);
    for (int i = gid; i < 16384; i += gsz) {       // W2bf[f2][f1] = bf16(W2[f1][f2])
        const int f2 = i >> 7, f1 = i & 127;
        W2bf[i] = bf1(W2[f1 * 128 + f2]);
    }
    for (int g = gid; g <= G; g += gsz) {          // gptr = lower_bound(batch,g)
        int lo = 0, hi = N;
        while (lo < hi) {
            int mid = (lo + hi) >> 1;
            if (batch[mid] < g) lo = mid + 1; else hi = mid;
        }
        gptr[g] = lo;
    }
}

// ---- per-bucket LDS sort -> exact CSR + dinv + xsb (self-scans bcnt) ----
// 512 threads on 256-node buckets: serial depth of the 3 edge passes
// halves (32 -> 16 iterations).
__global__ __launch_bounds__(512) void k_bsort(const unsigned* __restrict__ col1,
                                               const int* __restrict__ bcnt,
                                               int* __restrict__ col,
                                               int* __restrict__ rowptr,
                                               float* __restrict__ dinv,
                                               const float* __restrict__ x,
                                               unsigned short* __restrict__ xsb,
                                               int N, int E, int NB) {
    __shared__ unsigned ec[BCAP];
    __shared__ int bins[256], sc[256];
    __shared__ float dvb[256];
    const int b = blockIdx.x, t = threadIdx.x;

    // bucket-offset scan (196 ints, L2-hot): s0 = sum_{i<b} bcnt[i]
    if (t < 256) bins[t] = (t < NB) ? bcnt[t] : 0;
    __syncthreads();
    for (int off = 1; off < 256; off <<= 1) {
        int add = (t >= off && t < 256) ? bins[t - off] : 0;
        __syncthreads();
        if (t < 256) bins[t] += add;
        __syncthreads();
    }
    const int s0 = (b == 0) ? 0 : bins[b - 1];
    int cnt = bcnt[b];
    if (cnt > BCAP) cnt = BCAP;        // safety clamp (never hit for this E,N)
    __syncthreads();

    for (int i = t; i < cnt; i += 512) ec[i] = col1[(size_t)b * BCAP + i];
    if (t < 256) bins[t] = 0;
    __syncthreads();
    for (int i = t; i < cnt; i += 512) atomicAdd(&bins[ec[i] >> 16], 1);
    __syncthreads();
    int v = 0;
    if (t < 256) { v = bins[t]; sc[t] = v; }
    __syncthreads();
    for (int off = 1; off < 256; off <<= 1) {
        int add = (t >= off && t < 256) ? sc[t - off] : 0;
        __syncthreads();
        if (t < 256) sc[t] += add;
        __syncthreads();
    }
    int ex = 0;
    if (t < 256) ex = sc[t] - v;
    __syncthreads();
    const int n0 = b * 256;
    if (t < 256) {
        sc[t] = ex;          // exclusive local offsets
        bins[t] = 0;         // reuse as per-node cursor
        const float dv = rsqrtf((float)(v + 1));
        dvb[t] = dv;
        if (n0 + t < N) {
            rowptr[n0 + t] = s0 + ex;
            dinv[n0 + t] = dv;
        }
    }
    if (b == 0 && t == 0) rowptr[N] = E;
    __syncthreads();
    for (int i = t; i < cnt; i += 512) {
        unsigned e = ec[i];
        int dl = e >> 16;
        int p = sc[dl] + atomicAdd(&bins[dl], 1);
        col[s0 + p] = (int)(e & 0xffffu);
    }
    // xsb = bf16(x * dinv) for this bucket's nodes (coalesced)
    int nn = N - n0; if (nn > 256) nn = 256;
    const int lim = nn * 16;
    for (int i = t; i < lim; i += 512) {
        float vx = x[(size_t)n0 * 16 + i] * dvb[i >> 4];
        xsb[(size_t)n0 * 16 + i] = bf1(vx);
    }
}

// ---- FUSED gat16 + l12 (MFMA): 64 nodes/block, 512 threads (8 waves),
//      ~57 KB LDS -> 2 blocks/CU.
__global__ __launch_bounds__(512, 4) void k_l12g(
        const int* __restrict__ rowptr, const int* __restrict__ col,
        const unsigned short* __restrict__ xsb,
        const float* __restrict__ dinv,
        const float* __restrict__ W1, const float* __restrict__ b1,
        const unsigned short* __restrict__ W2bf,   // [f2][f1] bf16
        unsigned short* __restrict__ ht1b, int N) {
    __shared__ __align__(16) unsigned short W2s[128 * 136];  // [f2][f1] padded
    __shared__ __align__(16) unsigned short h1b[64 * 136];   // [node][f1] padded
    __shared__ __align__(16) float arow[64 * 16];
    __shared__ float dv[64];
    const int tid = threadIdx.x;
    const int n0 = blockIdx.x * 64;
    const int w = tid >> 6, lane = tid & 63;

    // stage W2^T (bf16): 128 rows x 16 uint4 segments
    for (int i = tid; i < 2048; i += 512) {
        const int f2 = i >> 4, seg = i & 15;
        *(uint4*)&W2s[f2 * 136 + seg * 8] = ((const uint4*)W2bf)[i];
    }
    if (tid < 64) dv[tid] = (n0 + tid < N) ? dinv[n0 + tid] : 0.f;

    // gather: 8 lanes per node (2 edge slots x 4 quarters), 8 nodes per wave
    {
        const int nd = lane >> 3, sub = lane & 7;
        const int slot = sub >> 2, qq = sub & 3;
        const int j = w * 8 + nd;
        const int n = n0 + j;
        float a[4] = {0.f, 0.f, 0.f, 0.f};
        if (n < N) {
            const int r1 = rowptr[n + 1];
            for (int e = rowptr[n] + slot; e < r1; e += 2)
                bf4acc(*(const uint2*)(xsb + (size_t)col[e] * 16 + qq * 4), a);
        }
#pragma unroll
        for (int i = 0; i < 4; ++i) a[i] += __shfl_xor(a[i], 4);
        if (slot == 0) {
            if (n < N) {   // self loop
                bf4acc(*(const uint2*)(xsb + (size_t)n * 16 + qq * 4), a);
                *(float4*)&arow[j * 16 + qq * 4] = make_float4(a[0], a[1], a[2], a[3]);
            } else {
                *(float4*)&arow[j * 16 + qq * 4] = make_float4(0.f, 0.f, 0.f, 0.f);
            }
        }
    }
    const int f = tid & 127, jg = tid >> 7;
    float w1r[16];
#pragma unroll
    for (int k = 0; k < 16; ++k) w1r[k] = W1[k * 128 + f];
    const float bias = b1[f];
    __syncthreads();

    // phase 1: h1 (bf16) into A-layout LDS
#pragma unroll 4
    for (int j = jg * 16; j < jg * 16 + 16; ++j) {
        float s = 0.f;
#pragma unroll
        for (int k = 0; k < 16; ++k) s += arow[j * 16 + k] * w1r[k];
        h1b[j * 136 + f] = bf1(fmaxf(dv[j] * s + bias, 0.f));
    }
    __syncthreads();

    // phase 2: MFMA, D[64x128] = h1[64x128] @ W2[128x128]
    const int mt = w & 3, nh = w >> 2;
    const int lm = lane & 15, quad = lane >> 4;
    f32x4 acc[4];
#pragma unroll
    for (int t = 0; t < 4; ++t) acc[t] = (f32x4){0.f, 0.f, 0.f, 0.f};
#pragma unroll
    for (int kb = 0; kb < 4; ++kb) {
        const short8 af = *(const short8*)&h1b[(mt * 16 + lm) * 136 + kb * 32 + quad * 8];
#pragma unroll
        for (int t = 0; t < 4; ++t) {
            const short8 bfv = *(const short8*)&W2s[(nh * 64 + t * 16 + lm) * 136 + kb * 32 + quad * 8];
            acc[t] = __builtin_amdgcn_mfma_f32_16x16x32_bf16(af, bfv, acc[t], 0, 0, 0);
        }
    }
    // epilogue: *dinv, pack bf16, store
#pragma unroll
    for (int t = 0; t < 4; ++t) {
        const int f2 = nh * 64 + t * 16 + lm;
#pragma unroll
        for (int r = 0; r < 4; ++r) {
            const int j = mt * 16 + quad * 4 + r;
            const int n = n0 + j;
            if (n < N)
                ht1b[(size_t)n * 128 + f2] = bf1(acc[t][r] * dv[j]);
        }
    }
}

// Wave/node gather (2 halves x 32 lanes x uint2, 4x unroll -> 8 rows in
// flight), then 8-node LDS run-merge (batch sorted) -> ~1 atomic set/block.
__global__ __launch_bounds__(512) void k_gat128pool(
        const int* __restrict__ rowptr, const int* __restrict__ col,
        const unsigned short* __restrict__ ht1b,
        const float* __restrict__ dinv, const float* __restrict__ b2,
        const int* __restrict__ batch, float* __restrict__ gsum, int N) {
    __shared__ __align__(16) float h2s[8][128];
    __shared__ int bats[8];
    const int wave = threadIdx.x >> 6, lane = threadIdx.x & 63;
    const int half = lane >> 5, q = lane & 31;
    const int n = blockIdx.x * 8 + wave;
    float a[4] = {0.f, 0.f, 0.f, 0.f};
    if (n < N) {
        const int r0 = rowptr[n], r1 = rowptr[n + 1];
        int j = r0 + half;
        while (j + 6 < r1) {
            int s0 = col[j], s1 = col[j + 2], s2 = col[j + 4], s3 = col[j + 6];
            uint2 u0 = *(const uint2*)(ht1b + (size_t)s0 * 128 + q * 4);
            uint2 u1 = *(const uint2*)(ht1b + (size_t)s1 * 128 + q * 4);
            uint2 u2 = *(const uint2*)(ht1b + (size_t)s2 * 128 + q * 4);
            uint2 u3 = *(const uint2*)(ht1b + (size_t)s3 * 128 + q * 4);
            bf4acc(u0, a); bf4acc(u1, a); bf4acc(u2, a); bf4acc(u3, a);
            j += 8;
        }
        while (j < r1) {
            bf4acc(*(const uint2*)(ht1b + (size_t)col[j] * 128 + q * 4), a);
            j += 2;
        }
        if (half == 0)  // self loop
            bf4acc(*(const uint2*)(ht1b + (size_t)n * 128 + q * 4), a);
    }
#pragma unroll
    for (int i = 0; i < 4; ++i) a[i] += __shfl_xor(a[i], 32);
    if (half == 0) {
        if (n < N) {
            const float d = dinv[n];
            const float4 bb = *(const float4*)(b2 + q * 4);
            h2s[wave][q * 4 + 0] = fmaxf(a[0] * d + bb.x, 0.f);
            h2s[wave][q * 4 + 1] = fmaxf(a[1] * d + bb.y, 0.f);
            h2s[wave][q * 4 + 2] = fmaxf(a[2] * d + bb.z, 0.f);
            h2s[wave][q * 4 + 3] = fmaxf(a[3] * d + bb.w, 0.f);
            if (q == 0) bats[wave] = batch[n];
        } else {
            h2s[wave][q * 4 + 0] = 0.f; h2s[wave][q * 4 + 1] = 0.f;
            h2s[wave][q * 4 + 2] = 0.f; h2s[wave][q * 4 + 3] = 0.f;
            if (q == 0) bats[wave] = -1;
        }
    }
    __syncthreads();
    if (threadIdx.x < 32) {
        const int qq = threadIdx.x;
        int bprev = bats[0];
        float4 acc4 = *(const float4*)&h2s[0][qq * 4];
#pragma unroll
        for (int wv = 1; wv < 8; ++wv) {
            const int bw = bats[wv];   // wave-uniform branch (LDS scalar)
            const float4 rv = *(const float4*)&h2s[wv][qq * 4];
            if (bw == bprev) {
                acc4.x += rv.x; acc4.y += rv.y; acc4.z += rv.z; acc4.w += rv.w;
            } else {
                if (bprev >= 0) {
                    float* gs = gsum + (size_t)bprev * 128 + qq * 4;
                    unsafeAtomicAdd(gs + 0, acc4.x); unsafeAtomicAdd(gs + 1, acc4.y);
                    unsafeAtomicAdd(gs + 2, acc4.z); unsafeAtomicAdd(gs + 3, acc4.w);
                }
                bprev = bw; acc4 = rv;
            }
        }
        if (bprev >= 0) {
            float* gs = gsum + (size_t)bprev * 128 + qq * 4;
            unsafeAtomicAdd(gs + 0, acc4.x); unsafeAtomicAdd(gs + 1, acc4.y);
            unsafeAtomicAdd(gs + 2, acc4.z); unsafeAtomicAdd(gs + 3, acc4.w);
        }
    }
}

__global__ __launch_bounds__(128) void k_head(
        const float* __restrict__ gsum, const int* __restrict__ gptr,
        const float* __restrict__ Wlab, const float* __restrict__ blab,
        const float* __restrict__ Wd1, const float* __restrict__ bd1,
        const float* __restrict__ Wd2, const float* __restrict__ bd2,
        float* __restrict__ out, int G) {
    __shared__ float sp[128];
    __shared__ float red[128];
    __shared__ float hd[64];
    const int g = blockIdx.x, t = threadIdx.x;
    const float cnt = (float)(gptr[g + 1] - gptr[g]);
    const float invc = 1.f / fmaxf(cnt, 1.f);
    const float pooled = gsum[g * 128 + t] * invc;
    sp[t] = pooled;
    red[t] = pooled * Wlab[t];
    __syncthreads();
    for (int off = 64; off > 0; off >>= 1) {
        if (t < off) red[t] += red[t + off];
        __syncthreads();
    }
    if (t == 0) out[g] = 1.f / (1.f + expf(-(red[0] + blab[0])));
    __syncthreads();   // red[] reuse barrier (label reduce fully consumed)
    // domain hidden: 2-way split-K across all 128 threads
    const int tt = t & 63, kh = t >> 6;
    const int f0 = kh * 64;
    float ps = 0.f;
#pragma unroll 8
    for (int f = f0; f < f0 + 64; ++f) ps += sp[f] * Wd1[f * 64 + tt];
    red[t] = ps;
    __syncthreads();
    if (t < 64) hd[t] = fmaxf(red[t] + red[t + 64] + bd1[t], 0.f);
    __syncthreads();
    if (t < 2) {
        float s = bd2[t];
        for (int j = 0; j < 64; ++j) s += hd[j] * Wd2[j * 2 + t];
        out[G + g * 2 + t] = s;
    }
}

extern "C" void kernel_launch(void* const* d_in, const int* in_sizes, int n_in,
                              void* d_out, int out_size, void* d_ws, size_t ws_size,
                              hipStream_t stream) {
    const float* x     = (const float*)d_in[0];
    const int*   ei    = (const int*)d_in[1];   // [2,E]: ei[e]=src, ei[E+e]=dst
    const int*   batch = (const int*)d_in[2];
    const float* W1    = (const float*)d_in[3];
    const float* b1    = (const float*)d_in[4];
    const float* W2    = (const float*)d_in[5];
    const float* b2    = (const float*)d_in[6];
    const float* Wlab  = (const float*)d_in[7];
    const float* blab  = (const float*)d_in[8];
    const float* Wd1   = (const float*)d_in[9];
    const float* bd1   = (const float*)d_in[10];
    const float* Wd2   = (const float*)d_in[11];
    const float* bd2   = (const float*)d_in[12];
    float* out = (float*)d_out;

    const int N = in_sizes[0] / 16;
    const int E = in_sizes[1] / 2;
    const int G = out_size / 3;
    const int NB = (N + 255) >> 8;             // node buckets of 256

    char* p = (char*)d_ws;
    auto carve = [&](size_t bytes) {
        void* r = (void*)p;
        p += (bytes + 255) & ~(size_t)255;
        return r;
    };
    int*      bcnt   = (int*)     carve(256 * 4);
    unsigned* col1   = (unsigned*)carve((size_t)NB * BCAP * 4);
    int*      col    = (int*)     carve((size_t)E * 4);
    int*      rowptr = (int*)     carve((size_t)(N + 1) * 4);
    int*      gptr   = (int*)     carve((size_t)(G + 1) * 4);
    float*    dinv   = (float*)   carve((size_t)N * 4);
    unsigned short* xsb  = (unsigned short*)carve((size_t)N * 16 * 2);
    unsigned short* W2bf = (unsigned short*)carve(128 * 128 * 2);
    unsigned short* ht1b = (unsigned short*)carve((size_t)N * 128 * 2);
    float*    gsum   = (float*)   carve((size_t)G * 128 * 4);

    const int FB = (E + TILE - 1) / TILE;      // bfill: one LDS tile/block

    hipMemsetAsync(bcnt, 0, 256 * 4, stream);
    k_bfill  <<<FB, 512, 0, stream>>>(ei, bcnt, col1, batch, gptr, gsum, W2,
                                      W2bf, E, NB, N, G);
    k_bsort  <<<NB, 512, 0, stream>>>(col1, bcnt, col, rowptr, dinv, x, xsb,
                                      N, E, NB);
    k_l12g   <<<(N + 63) / 64, 512, 0, stream>>>(rowptr, col, xsb, dinv,
                                                 W1, b1, W2bf, ht1b, N);
    k_gat128pool<<<(N + 7) / 8, 512, 0, stream>>>(rowptr, col, ht1b, dinv, b2,
                                                  batch, gsum, N);
    k_head   <<<G, 128, 0, stream>>>(gsum, gptr, Wlab, blab, Wd1, bd1, Wd2,
                                     bd2, out, G);
}

// Round 9
// 210.413 us; speedup vs baseline: 1.3917x; 1.0557x over previous
//
#include <hip/hip_runtime.h>
#include <hip/hip_fp16.h>
#include <math.h>

// GCN forward, CSR-gather; bf16 xs/W2; MFMA layer-2 dense; block-
// aggregated pooling. CSR build = single-pass fixed-capacity bucket sort.
// R9: ht1 (layer-2 gather table) stored as FP8 E5M2 (top byte of fp16):
// halves the gather's logical traffic (410->205MB) and working set
// (12.8->6.4MB, closer to 4MB/XCD L2 -> miss rate drops too). Encode =
// f32->f16 RNE + RNE top-byte round; decode = byte<<8 into half2 + 2x
// v_cvt_f32_f16 -- no fp8 builtins needed. Accuracy: per-element quant
// noise is uncorrelated across the ~3100 edges pooled per graph ->
// output delta ~1e-4, 20x below the existing 0.00195 absmax (which is
// correlated W2/xsb bf16 error that pooling can't average). Gather-fetch
// model (R0/R3/R4): t ~ hit-service(logical) + 0.21us/MB * FETCH.
// R8 build-kernel serial-depth cuts were null -> build kernels at floor.
// Requires N <= 65536 (src packed in 16 bits, bucket fits 8 bits).

#define BCAP 12288   // bucket capacity (mean fill ~8.2K, 45 sigma headroom)
#define TILE 8192    // bfill edges per block (LDS-staged, 64KB)

typedef __attribute__((ext_vector_type(8))) short short8;   // 8 bf16 (4 VGPRs)
typedef __attribute__((ext_vector_type(4))) float f32x4;    // MFMA accumulator

__device__ __forceinline__ void bf4acc(uint2 u, float* a) {
    a[0] += __uint_as_float(u.x << 16);
    a[1] += __uint_as_float(u.x & 0xffff0000u);
    a[2] += __uint_as_float(u.y << 16);
    a[3] += __uint_as_float(u.y & 0xffff0000u);
}

__device__ __forceinline__ unsigned short bf1(float a) {    // RNE bf16
    unsigned ua = __float_as_uint(a);
    return (unsigned short)((ua + 0x7fffu + ((ua >> 16) & 1u)) >> 16);
}

__device__ __forceinline__ unsigned char e5m2q(float v) {   // RNE e5m2
    const unsigned hb = (unsigned)__half_as_ushort(__float2half(v));
    return (unsigned char)((hb + 0x7fu + ((hb >> 8) & 1u)) >> 8);
}

// decode 4 e5m2 bytes (features 4k..4k+3) and accumulate
__device__ __forceinline__ void e5acc(unsigned u, float* a) {
    unsigned h01 = ((u & 0x000000ffu) << 8) | ((u & 0x0000ff00u) << 16);
    unsigned h23 = ((u & 0x00ff0000u) >> 8) | (u & 0xff000000u);
    const __half2 x01 = *reinterpret_cast<const __half2*>(&h01);
    const __half2 x23 = *reinterpret_cast<const __half2*>(&h23);
    const float2 f01 = __half22float2(x01);
    const float2 f23 = __half22float2(x23);
    a[0] += f01.x; a[1] += f01.y;
    a[2] += f23.x; a[3] += f23.y;
}

// ---- LDS-staged bucketed fill: 8192-edge tile -> local counting sort ->
//      coalesced per-bucket run copy-out (~32 edges = 128B per run) ----
__global__ __launch_bounds__(512) void k_bfill(
        const int* __restrict__ ei, int* __restrict__ bcnt,
        unsigned* __restrict__ col1,
        const int* __restrict__ batch, int* __restrict__ gptr,
        float* __restrict__ gsum, const float* __restrict__ W2,
        unsigned short* __restrict__ W2bf,
        int E, int NB, int N, int G) {
    __shared__ unsigned ev[TILE];      // (b<<24)|(dstLocal<<16)|src
    __shared__ unsigned es[TILE];      // bucket-sorted
    __shared__ int bins[256], scn[256], cur[256], gbase[256];
    const int t = threadIdx.x;
    const int e0 = blockIdx.x * TILE;
    int cnt = E - e0; if (cnt > TILE) cnt = TILE;

    if (t < 256) bins[t] = 0;
    __syncthreads();
    for (int i = t; i < cnt; i += 512) {        // stage + histogram
        const int d = ei[E + e0 + i];
        const int s = ei[e0 + i];
        const unsigned b = (unsigned)d >> 8;    // NB <= 256 -> fits 8 bits
        ev[i] = (b << 24) | ((unsigned)(d & 255) << 16) | (unsigned)s;
        atomicAdd(&bins[b], 1);
    }
    __syncthreads();
    int v = 0;
    if (t < 256) { v = bins[t]; scn[t] = v; }
    __syncthreads();
    for (int off = 1; off < 256; off <<= 1) {   // inclusive scan (256-wide)
        int add = (t >= off && t < 256) ? scn[t - off] : 0;
        __syncthreads();
        if (t < 256) scn[t] += add;
        __syncthreads();
    }
    int ex = 0;
    if (t < 256) ex = scn[t] - v;
    __syncthreads();
    if (t < 256) {
        scn[t] = ex;                            // exclusive local offsets
        cur[t] = 0;
        gbase[t] = v ? atomicAdd(&bcnt[t], v) : 0;  // reserve global run
    }
    __syncthreads();
    for (int i = t; i < cnt; i += 512) {        // scatter within LDS
        const unsigned e = ev[i];
        const int b = e >> 24;
        const int p = scn[b] + atomicAdd(&cur[b], 1);
        es[p] = e;
    }
    __syncthreads();
    for (int i = t; i < cnt; i += 512) {        // coalesced copy-out
        const unsigned e = es[i];
        const int b = e >> 24;
        const int pos = gbase[b] + (i - scn[b]);
        if (pos < BCAP)
            col1[(size_t)b * BCAP + pos] = e & 0xffffffu;
    }

    // distributed prep tails
    const int gid = blockIdx.x * 512 + t;
    const int gsz = gridDim.x * 512;
    for (int i = gid; i < G * 32; i += gsz)        // gsum = 0 (float4)
        ((float4*)gsum)[i] = make_float4(0.f, 0.f, 0.f, 0.f);
    for (int i = gid; i < 16384; i += gsz) {       // W2bf[f2][f1] = bf16(W2[f1][f2])
        const int f2 = i >> 7, f1 = i & 127;
        W2bf[i] = bf1(W2[f1 * 128 + f2]);
    }
    for (int g = gid; g <= G; g += gsz) {          // gptr = lower_bound(batch,g)
        int lo = 0, hi = N;
        while (lo < hi) {
            int mid = (lo + hi) >> 1;
            if (batch[mid] < g) lo = mid + 1; else hi = mid;
        }
        gptr[g] = lo;
    }
}

// ---- per-bucket LDS sort -> exact CSR + dinv + xsb (self-scans bcnt) ----
__global__ __launch_bounds__(512) void k_bsort(const unsigned* __restrict__ col1,
                                               const int* __restrict__ bcnt,
                                               int* __restrict__ col,
                                               int* __restrict__ rowptr,
                                               float* __restrict__ dinv,
                                               const float* __restrict__ x,
                                               unsigned short* __restrict__ xsb,
                                               int N, int E, int NB) {
    __shared__ unsigned ec[BCAP];
    __shared__ int bins[256], sc[256];
    __shared__ float dvb[256];
    const int b = blockIdx.x, t = threadIdx.x;

    // bucket-offset scan (196 ints, L2-hot): s0 = sum_{i<b} bcnt[i]
    if (t < 256) bins[t] = (t < NB) ? bcnt[t] : 0;
    __syncthreads();
    for (int off = 1; off < 256; off <<= 1) {
        int add = (t >= off && t < 256) ? bins[t - off] : 0;
        __syncthreads();
        if (t < 256) bins[t] += add;
        __syncthreads();
    }
    const int s0 = (b == 0) ? 0 : bins[b - 1];
    int cnt = bcnt[b];
    if (cnt > BCAP) cnt = BCAP;        // safety clamp (never hit for this E,N)
    __syncthreads();

    for (int i = t; i < cnt; i += 512) ec[i] = col1[(size_t)b * BCAP + i];
    if (t < 256) bins[t] = 0;
    __syncthreads();
    for (int i = t; i < cnt; i += 512) atomicAdd(&bins[ec[i] >> 16], 1);
    __syncthreads();
    int v = 0;
    if (t < 256) { v = bins[t]; sc[t] = v; }
    __syncthreads();
    for (int off = 1; off < 256; off <<= 1) {
        int add = (t >= off && t < 256) ? sc[t - off] : 0;
        __syncthreads();
        if (t < 256) sc[t] += add;
        __syncthreads();
    }
    int ex = 0;
    if (t < 256) ex = sc[t] - v;
    __syncthreads();
    const int n0 = b * 256;
    if (t < 256) {
        sc[t] = ex;          // exclusive local offsets
        bins[t] = 0;         // reuse as per-node cursor
        const float dv = rsqrtf((float)(v + 1));
        dvb[t] = dv;
        if (n0 + t < N) {
            rowptr[n0 + t] = s0 + ex;
            dinv[n0 + t] = dv;
        }
    }
    if (b == 0 && t == 0) rowptr[N] = E;
    __syncthreads();
    for (int i = t; i < cnt; i += 512) {
        unsigned e = ec[i];
        int dl = e >> 16;
        int p = sc[dl] + atomicAdd(&bins[dl], 1);
        col[s0 + p] = (int)(e & 0xffffu);
    }
    // xsb = bf16(x * dinv) for this bucket's nodes (coalesced)
    int nn = N - n0; if (nn > 256) nn = 256;
    const int lim = nn * 16;
    for (int i = t; i < lim; i += 512) {
        float vx = x[(size_t)n0 * 16 + i] * dvb[i >> 4];
        xsb[(size_t)n0 * 16 + i] = bf1(vx);
    }
}

// ---- FUSED gat16 + l12 (MFMA): 64 nodes/block, 512 threads (8 waves),
//      ~57 KB LDS -> 2 blocks/CU. Epilogue stores ht1 as e5m2 bytes.
__global__ __launch_bounds__(512, 4) void k_l12g(
        const int* __restrict__ rowptr, const int* __restrict__ col,
        const unsigned short* __restrict__ xsb,
        const float* __restrict__ dinv,
        const float* __restrict__ W1, const float* __restrict__ b1,
        const unsigned short* __restrict__ W2bf,   // [f2][f1] bf16
        unsigned char* __restrict__ ht1q, int N) {
    __shared__ __align__(16) unsigned short W2s[128 * 136];  // [f2][f1] padded
    __shared__ __align__(16) unsigned short h1b[64 * 136];   // [node][f1] padded
    __shared__ __align__(16) float arow[64 * 16];
    __shared__ float dv[64];
    const int tid = threadIdx.x;
    const int n0 = blockIdx.x * 64;
    const int w = tid >> 6, lane = tid & 63;

    // stage W2^T (bf16): 128 rows x 16 uint4 segments
    for (int i = tid; i < 2048; i += 512) {
        const int f2 = i >> 4, seg = i & 15;
        *(uint4*)&W2s[f2 * 136 + seg * 8] = ((const uint4*)W2bf)[i];
    }
    if (tid < 64) dv[tid] = (n0 + tid < N) ? dinv[n0 + tid] : 0.f;

    // gather: 8 lanes per node (2 edge slots x 4 quarters), 8 nodes per wave
    {
        const int nd = lane >> 3, sub = lane & 7;
        const int slot = sub >> 2, qq = sub & 3;
        const int j = w * 8 + nd;
        const int n = n0 + j;
        float a[4] = {0.f, 0.f, 0.f, 0.f};
        if (n < N) {
            const int r1 = rowptr[n + 1];
            for (int e = rowptr[n] + slot; e < r1; e += 2)
                bf4acc(*(const uint2*)(xsb + (size_t)col[e] * 16 + qq * 4), a);
        }
#pragma unroll
        for (int i = 0; i < 4; ++i) a[i] += __shfl_xor(a[i], 4);
        if (slot == 0) {
            if (n < N) {   // self loop
                bf4acc(*(const uint2*)(xsb + (size_t)n * 16 + qq * 4), a);
                *(float4*)&arow[j * 16 + qq * 4] = make_float4(a[0], a[1], a[2], a[3]);
            } else {
                *(float4*)&arow[j * 16 + qq * 4] = make_float4(0.f, 0.f, 0.f, 0.f);
            }
        }
    }
    const int f = tid & 127, jg = tid >> 7;
    float w1r[16];
#pragma unroll
    for (int k = 0; k < 16; ++k) w1r[k] = W1[k * 128 + f];
    const float bias = b1[f];
    __syncthreads();

    // phase 1: h1 (bf16) into A-layout LDS
#pragma unroll 4
    for (int j = jg * 16; j < jg * 16 + 16; ++j) {
        float s = 0.f;
#pragma unroll
        for (int k = 0; k < 16; ++k) s += arow[j * 16 + k] * w1r[k];
        h1b[j * 136 + f] = bf1(fmaxf(dv[j] * s + bias, 0.f));
    }
    __syncthreads();

    // phase 2: MFMA, D[64x128] = h1[64x128] @ W2[128x128]
    const int mt = w & 3, nh = w >> 2;
    const int lm = lane & 15, quad = lane >> 4;
    f32x4 acc[4];
#pragma unroll
    for (int t = 0; t < 4; ++t) acc[t] = (f32x4){0.f, 0.f, 0.f, 0.f};
#pragma unroll
    for (int kb = 0; kb < 4; ++kb) {
        const short8 af = *(const short8*)&h1b[(mt * 16 + lm) * 136 + kb * 32 + quad * 8];
#pragma unroll
        for (int t = 0; t < 4; ++t) {
            const short8 bfv = *(const short8*)&W2s[(nh * 64 + t * 16 + lm) * 136 + kb * 32 + quad * 8];
            acc[t] = __builtin_amdgcn_mfma_f32_16x16x32_bf16(af, bfv, acc[t], 0, 0, 0);
        }
    }
    // epilogue: *dinv, quantize e5m2, store bytes
#pragma unroll
    for (int t = 0; t < 4; ++t) {
        const int f2 = nh * 64 + t * 16 + lm;
#pragma unroll
        for (int r = 0; r < 4; ++r) {
            const int j = mt * 16 + quad * 4 + r;
            const int n = n0 + j;
            if (n < N)
                ht1q[(size_t)n * 128 + f2] = e5m2q(acc[t][r] * dv[j]);
        }
    }
}

// Wave/node gather (2 halves x 32 lanes x uint(4 e5m2), 4x unroll -> 8
// rows in flight), then 8-node LDS run-merge (batch sorted) -> ~1 atomic
// set/block. Row = 128B e5m2.
__global__ __launch_bounds__(512) void k_gat128pool(
        const int* __restrict__ rowptr, const int* __restrict__ col,
        const unsigned char* __restrict__ ht1q,
        const float* __restrict__ dinv, const float* __restrict__ b2,
        const int* __restrict__ batch, float* __restrict__ gsum, int N) {
    __shared__ __align__(16) float h2s[8][128];
    __shared__ int bats[8];
    const int wave = threadIdx.x >> 6, lane = threadIdx.x & 63;
    const int half = lane >> 5, q = lane & 31;
    const int n = blockIdx.x * 8 + wave;
    float a[4] = {0.f, 0.f, 0.f, 0.f};
    if (n < N) {
        const int r0 = rowptr[n], r1 = rowptr[n + 1];
        int j = r0 + half;
        while (j + 6 < r1) {
            int s0 = col[j], s1 = col[j + 2], s2 = col[j + 4], s3 = col[j + 6];
            unsigned u0 = *(const unsigned*)(ht1q + (size_t)s0 * 128 + q * 4);
            unsigned u1 = *(const unsigned*)(ht1q + (size_t)s1 * 128 + q * 4);
            unsigned u2 = *(const unsigned*)(ht1q + (size_t)s2 * 128 + q * 4);
            unsigned u3 = *(const unsigned*)(ht1q + (size_t)s3 * 128 + q * 4);
            e5acc(u0, a); e5acc(u1, a); e5acc(u2, a); e5acc(u3, a);
            j += 8;
        }
        while (j < r1) {
            e5acc(*(const unsigned*)(ht1q + (size_t)col[j] * 128 + q * 4), a);
            j += 2;
        }
        if (half == 0)  // self loop
            e5acc(*(const unsigned*)(ht1q + (size_t)n * 128 + q * 4), a);
    }
#pragma unroll
    for (int i = 0; i < 4; ++i) a[i] += __shfl_xor(a[i], 32);
    if (half == 0) {
        if (n < N) {
            const float d = dinv[n];
            const float4 bb = *(const float4*)(b2 + q * 4);
            h2s[wave][q * 4 + 0] = fmaxf(a[0] * d + bb.x, 0.f);
            h2s[wave][q * 4 + 1] = fmaxf(a[1] * d + bb.y, 0.f);
            h2s[wave][q * 4 + 2] = fmaxf(a[2] * d + bb.z, 0.f);
            h2s[wave][q * 4 + 3] = fmaxf(a[3] * d + bb.w, 0.f);
            if (q == 0) bats[wave] = batch[n];
        } else {
            h2s[wave][q * 4 + 0] = 0.f; h2s[wave][q * 4 + 1] = 0.f;
            h2s[wave][q * 4 + 2] = 0.f; h2s[wave][q * 4 + 3] = 0.f;
            if (q == 0) bats[wave] = -1;
        }
    }
    __syncthreads();
    if (threadIdx.x < 32) {
        const int qq = threadIdx.x;
        int bprev = bats[0];
        float4 acc4 = *(const float4*)&h2s[0][qq * 4];
#pragma unroll
        for (int wv = 1; wv < 8; ++wv) {
            const int bw = bats[wv];   // wave-uniform branch (LDS scalar)
            const float4 rv = *(const float4*)&h2s[wv][qq * 4];
            if (bw == bprev) {
                acc4.x += rv.x; acc4.y += rv.y; acc4.z += rv.z; acc4.w += rv.w;
            } else {
                if (bprev >= 0) {
                    float* gs = gsum + (size_t)bprev * 128 + qq * 4;
                    unsafeAtomicAdd(gs + 0, acc4.x); unsafeAtomicAdd(gs + 1, acc4.y);
                    unsafeAtomicAdd(gs + 2, acc4.z); unsafeAtomicAdd(gs + 3, acc4.w);
                }
                bprev = bw; acc4 = rv;
            }
        }
        if (bprev >= 0) {
            float* gs = gsum + (size_t)bprev * 128 + qq * 4;
            unsafeAtomicAdd(gs + 0, acc4.x); unsafeAtomicAdd(gs + 1, acc4.y);
            unsafeAtomicAdd(gs + 2, acc4.z); unsafeAtomicAdd(gs + 3, acc4.w);
        }
    }
}

__global__ __launch_bounds__(128) void k_head(
        const float* __restrict__ gsum, const int* __restrict__ gptr,
        const float* __restrict__ Wlab, const float* __restrict__ blab,
        const float* __restrict__ Wd1, const float* __restrict__ bd1,
        const float* __restrict__ Wd2, const float* __restrict__ bd2,
        float* __restrict__ out, int G) {
    __shared__ float sp[128];
    __shared__ float red[128];
    __shared__ float hd[64];
    const int g = blockIdx.x, t = threadIdx.x;
    const float cnt = (float)(gptr[g + 1] - gptr[g]);
    const float invc = 1.f / fmaxf(cnt, 1.f);
    const float pooled = gsum[g * 128 + t] * invc;
    sp[t] = pooled;
    red[t] = pooled * Wlab[t];
    __syncthreads();
    for (int off = 64; off > 0; off >>= 1) {
        if (t < off) red[t] += red[t + off];
        __syncthreads();
    }
    if (t == 0) out[g] = 1.f / (1.f + expf(-(red[0] + blab[0])));
    __syncthreads();   // red[] reuse barrier (label reduce fully consumed)
    // domain hidden: 2-way split-K across all 128 threads
    const int tt = t & 63, kh = t >> 6;
    const int f0 = kh * 64;
    float ps = 0.f;
#pragma unroll 8
    for (int f = f0; f < f0 + 64; ++f) ps += sp[f] * Wd1[f * 64 + tt];
    red[t] = ps;
    __syncthreads();
    if (t < 64) hd[t] = fmaxf(red[t] + red[t + 64] + bd1[t], 0.f);
    __syncthreads();
    if (t < 2) {
        float s = bd2[t];
        for (int j = 0; j < 64; ++j) s += hd[j] * Wd2[j * 2 + t];
        out[G + g * 2 + t] = s;
    }
}

extern "C" void kernel_launch(void* const* d_in, const int* in_sizes, int n_in,
                              void* d_out, int out_size, void* d_ws, size_t ws_size,
                              hipStream_t stream) {
    const float* x     = (const float*)d_in[0];
    const int*   ei    = (const int*)d_in[1];   // [2,E]: ei[e]=src, ei[E+e]=dst
    const int*   batch = (const int*)d_in[2];
    const float* W1    = (const float*)d_in[3];
    const float* b1    = (const float*)d_in[4];
    const float* W2    = (const float*)d_in[5];
    const float* b2    = (const float*)d_in[6];
    const float* Wlab  = (const float*)d_in[7];
    const float* blab  = (const float*)d_in[8];
    const float* Wd1   = (const float*)d_in[9];
    const float* bd1   = (const float*)d_in[10];
    const float* Wd2   = (const float*)d_in[11];
    const float* bd2   = (const float*)d_in[12];
    float* out = (float*)d_out;

    const int N = in_sizes[0] / 16;
    const int E = in_sizes[1] / 2;
    const int G = out_size / 3;
    const int NB = (N + 255) >> 8;             // node buckets of 256

    char* p = (char*)d_ws;
    auto carve = [&](size_t bytes) {
        void* r = (void*)p;
        p += (bytes + 255) & ~(size_t)255;
        return r;
    };
    int*      bcnt   = (int*)     carve(256 * 4);
    unsigned* col1   = (unsigned*)carve((size_t)NB * BCAP * 4);
    int*      col    = (int*)     carve((size_t)E * 4);
    int*      rowptr = (int*)     carve((size_t)(N + 1) * 4);
    int*      gptr   = (int*)     carve((size_t)(G + 1) * 4);
    float*    dinv   = (float*)   carve((size_t)N * 4);
    unsigned short* xsb  = (unsigned short*)carve((size_t)N * 16 * 2);
    unsigned short* W2bf = (unsigned short*)carve(128 * 128 * 2);
    unsigned char*  ht1q = (unsigned char*) carve((size_t)N * 128);
    float*    gsum   = (float*)   carve((size_t)G * 128 * 4);

    const int FB = (E + TILE - 1) / TILE;      // bfill: one LDS tile/block

    hipMemsetAsync(bcnt, 0, 256 * 4, stream);
    k_bfill  <<<FB, 512, 0, stream>>>(ei, bcnt, col1, batch, gptr, gsum, W2,
                                      W2bf, E, NB, N, G);
    k_bsort  <<<NB, 512, 0, stream>>>(col1, bcnt, col, rowptr, dinv, x, xsb,
                                      N, E, NB);
    k_l12g   <<<(N + 63) / 64, 512, 0, stream>>>(rowptr, col, xsb, dinv,
                                                 W1, b1, W2bf, ht1q, N);
    k_gat128pool<<<(N + 7) / 8, 512, 0, stream>>>(rowptr, col, ht1q, dinv, b2,
                                                  batch, gsum, N);
    k_head   <<<G, 128, 0, stream>>>(gsum, gptr, Wlab, blab, Wd1, bd1, Wd2,
                                     bd2, out, G);
}

// Round 10
// 208.319 us; speedup vs baseline: 1.4057x; 1.0101x over previous
//
#include <hip/hip_runtime.h>
#include <hip/hip_fp16.h>
#include <math.h>

// GCN forward, CSR-gather; bf16 xs/W2; MFMA layer-2 dense; block-
// aggregated pooling. CSR build = single-pass fixed-capacity bucket sort.
// R10: layer-2 gather decode switched to HW v_cvt_pk_f32_bf8 (bf8==e5m2,
// bit-identical to the R9 bit-trick which stays as a __has_builtin
// fallback): 4-feature decode 10 VALU -> 6. R9 counters: FETCH 51.5MB ==
// compulsory floor (8 XCD x 6.4MB table), VALUBusy 48% -> gather is now
// VALU/latency-mixed; decode is the biggest term (~26us of 53.4).
// R8 build-kernel serial-depth cuts were null -> build kernels at floor.
// Requires N <= 65536 (src packed in 16 bits, bucket fits 8 bits).

#define BCAP 12288   // bucket capacity (mean fill ~8.2K, 45 sigma headroom)
#define TILE 8192    // bfill edges per block (LDS-staged, 64KB)

typedef __attribute__((ext_vector_type(8))) short short8;   // 8 bf16 (4 VGPRs)
typedef __attribute__((ext_vector_type(4))) float f32x4;    // MFMA accumulator
typedef __attribute__((ext_vector_type(2))) float f32x2;

__device__ __forceinline__ void bf4acc(uint2 u, float* a) {
    a[0] += __uint_as_float(u.x << 16);
    a[1] += __uint_as_float(u.x & 0xffff0000u);
    a[2] += __uint_as_float(u.y << 16);
    a[3] += __uint_as_float(u.y & 0xffff0000u);
}

__device__ __forceinline__ unsigned short bf1(float a) {    // RNE bf16
    unsigned ua = __float_as_uint(a);
    return (unsigned short)((ua + 0x7fffu + ((ua >> 16) & 1u)) >> 16);
}

__device__ __forceinline__ unsigned char e5m2q(float v) {   // RNE e5m2
    const unsigned hb = (unsigned)__half_as_ushort(__float2half(v));
    return (unsigned char)((hb + 0x7fu + ((hb >> 8) & 1u)) >> 8);
}

// decode 4 e5m2 bytes (features 4k..4k+3) and accumulate.
// bf8 (AMD) == e5m2 (OCP): HW cvt is bit-exact vs the fp16-top-byte trick.
__device__ __forceinline__ void e5acc(unsigned u, float* a) {
#if __has_builtin(__builtin_amdgcn_cvt_pk_f32_bf8)
    const f32x2 lo = __builtin_amdgcn_cvt_pk_f32_bf8((int)u, false);
    const f32x2 hi = __builtin_amdgcn_cvt_pk_f32_bf8((int)u, true);
    a[0] += lo[0]; a[1] += lo[1];
    a[2] += hi[0]; a[3] += hi[1];
#else
    unsigned h01 = ((u & 0x000000ffu) << 8) | ((u & 0x0000ff00u) << 16);
    unsigned h23 = ((u & 0x00ff0000u) >> 8) | (u & 0xff000000u);
    const __half2 x01 = *reinterpret_cast<const __half2*>(&h01);
    const __half2 x23 = *reinterpret_cast<const __half2*>(&h23);
    const float2 f01 = __half22float2(x01);
    const float2 f23 = __half22float2(x23);
    a[0] += f01.x; a[1] += f01.y;
    a[2] += f23.x; a[3] += f23.y;
#endif
}

// ---- LDS-staged bucketed fill: 8192-edge tile -> local counting sort ->
//      coalesced per-bucket run copy-out (~32 edges = 128B per run) ----
__global__ __launch_bounds__(512) void k_bfill(
        const int* __restrict__ ei, int* __restrict__ bcnt,
        unsigned* __restrict__ col1,
        const int* __restrict__ batch, int* __restrict__ gptr,
        float* __restrict__ gsum, const float* __restrict__ W2,
        unsigned short* __restrict__ W2bf,
        int E, int NB, int N, int G) {
    __shared__ unsigned ev[TILE];      // (b<<24)|(dstLocal<<16)|src
    __shared__ unsigned es[TILE];      // bucket-sorted
    __shared__ int bins[256], scn[256], cur[256], gbase[256];
    const int t = threadIdx.x;
    const int e0 = blockIdx.x * TILE;
    int cnt = E - e0; if (cnt > TILE) cnt = TILE;

    if (t < 256) bins[t] = 0;
    __syncthreads();
    for (int i = t; i < cnt; i += 512) {        // stage + histogram
        const int d = ei[E + e0 + i];
        const int s = ei[e0 + i];
        const unsigned b = (unsigned)d >> 8;    // NB <= 256 -> fits 8 bits
        ev[i] = (b << 24) | ((unsigned)(d & 255) << 16) | (unsigned)s;
        atomicAdd(&bins[b], 1);
    }
    __syncthreads();
    int v = 0;
    if (t < 256) { v = bins[t]; scn[t] = v; }
    __syncthreads();
    for (int off = 1; off < 256; off <<= 1) {   // inclusive scan (256-wide)
        int add = (t >= off && t < 256) ? scn[t - off] : 0;
        __syncthreads();
        if (t < 256) scn[t] += add;
        __syncthreads();
    }
    int ex = 0;
    if (t < 256) ex = scn[t] - v;
    __syncthreads();
    if (t < 256) {
        scn[t] = ex;                            // exclusive local offsets
        cur[t] = 0;
        gbase[t] = v ? atomicAdd(&bcnt[t], v) : 0;  // reserve global run
    }
    __syncthreads();
    for (int i = t; i < cnt; i += 512) {        // scatter within LDS
        const unsigned e = ev[i];
        const int b = e >> 24;
        const int p = scn[b] + atomicAdd(&cur[b], 1);
        es[p] = e;
    }
    __syncthreads();
    for (int i = t; i < cnt; i += 512) {        // coalesced copy-out
        const unsigned e = es[i];
        const int b = e >> 24;
        const int pos = gbase[b] + (i - scn[b]);
        if (pos < BCAP)
            col1[(size_t)b * BCAP + pos] = e & 0xffffffu;
    }

    // distributed prep tails
    const int gid = blockIdx.x * 512 + t;
    const int gsz = gridDim.x * 512;
    for (int i = gid; i < G * 32; i += gsz)        // gsum = 0 (float4)
        ((float4*)gsum)[i] = make_float4(0.f, 0.f, 0.f, 0.f);
    for (int i = gid; i < 16384; i += gsz) {       // W2bf[f2][f1] = bf16(W2[f1][f2])
        const int f2 = i >> 7, f1 = i & 127;
        W2bf[i] = bf1(W2[f1 * 128 + f2]);
    }
    for (int g = gid; g <= G; g += gsz) {          // gptr = lower_bound(batch,g)
        int lo = 0, hi = N;
        while (lo < hi) {
            int mid = (lo + hi) >> 1;
            if (batch[mid] < g) lo = mid + 1; else hi = mid;
        }
        gptr[g] = lo;
    }
}

// ---- per-bucket LDS sort -> exact CSR + dinv + xsb (self-scans bcnt) ----
__global__ __launch_bounds__(512) void k_bsort(const unsigned* __restrict__ col1,
                                               const int* __restrict__ bcnt,
                                               int* __restrict__ col,
                                               int* __restrict__ rowptr,
                                               float* __restrict__ dinv,
                                               const float* __restrict__ x,
                                               unsigned short* __restrict__ xsb,
                                               int N, int E, int NB) {
    __shared__ unsigned ec[BCAP];
    __shared__ int bins[256], sc[256];
    __shared__ float dvb[256];
    const int b = blockIdx.x, t = threadIdx.x;

    // bucket-offset scan (196 ints, L2-hot): s0 = sum_{i<b} bcnt[i]
    if (t < 256) bins[t] = (t < NB) ? bcnt[t] : 0;
    __syncthreads();
    for (int off = 1; off < 256; off <<= 1) {
        int add = (t >= off && t < 256) ? bins[t - off] : 0;
        __syncthreads();
        if (t < 256) bins[t] += add;
        __syncthreads();
    }
    const int s0 = (b == 0) ? 0 : bins[b - 1];
    int cnt = bcnt[b];
    if (cnt > BCAP) cnt = BCAP;        // safety clamp (never hit for this E,N)
    __syncthreads();

    for (int i = t; i < cnt; i += 512) ec[i] = col1[(size_t)b * BCAP + i];
    if (t < 256) bins[t] = 0;
    __syncthreads();
    for (int i = t; i < cnt; i += 512) atomicAdd(&bins[ec[i] >> 16], 1);
    __syncthreads();
    int v = 0;
    if (t < 256) { v = bins[t]; sc[t] = v; }
    __syncthreads();
    for (int off = 1; off < 256; off <<= 1) {
        int add = (t >= off && t < 256) ? sc[t - off] : 0;
        __syncthreads();
        if (t < 256) sc[t] += add;
        __syncthreads();
    }
    int ex = 0;
    if (t < 256) ex = sc[t] - v;
    __syncthreads();
    const int n0 = b * 256;
    if (t < 256) {
        sc[t] = ex;          // exclusive local offsets
        bins[t] = 0;         // reuse as per-node cursor
        const float dv = rsqrtf((float)(v + 1));
        dvb[t] = dv;
        if (n0 + t < N) {
            rowptr[n0 + t] = s0 + ex;
            dinv[n0 + t] = dv;
        }
    }
    if (b == 0 && t == 0) rowptr[N] = E;
    __syncthreads();
    for (int i = t; i < cnt; i += 512) {
        unsigned e = ec[i];
        int dl = e >> 16;
        int p = sc[dl] + atomicAdd(&bins[dl], 1);
        col[s0 + p] = (int)(e & 0xffffu);
    }
    // xsb = bf16(x * dinv) for this bucket's nodes (coalesced)
    int nn = N - n0; if (nn > 256) nn = 256;
    const int lim = nn * 16;
    for (int i = t; i < lim; i += 512) {
        float vx = x[(size_t)n0 * 16 + i] * dvb[i >> 4];
        xsb[(size_t)n0 * 16 + i] = bf1(vx);
    }
}

// ---- FUSED gat16 + l12 (MFMA): 64 nodes/block, 512 threads (8 waves),
//      ~57 KB LDS -> 2 blocks/CU. Epilogue stores ht1 as e5m2 bytes.
__global__ __launch_bounds__(512, 4) void k_l12g(
        const int* __restrict__ rowptr, const int* __restrict__ col,
        const unsigned short* __restrict__ xsb,
        const float* __restrict__ dinv,
        const float* __restrict__ W1, const float* __restrict__ b1,
        const unsigned short* __restrict__ W2bf,   // [f2][f1] bf16
        unsigned char* __restrict__ ht1q, int N) {
    __shared__ __align__(16) unsigned short W2s[128 * 136];  // [f2][f1] padded
    __shared__ __align__(16) unsigned short h1b[64 * 136];   // [node][f1] padded
    __shared__ __align__(16) float arow[64 * 16];
    __shared__ float dv[64];
    const int tid = threadIdx.x;
    const int n0 = blockIdx.x * 64;
    const int w = tid >> 6, lane = tid & 63;

    // stage W2^T (bf16): 128 rows x 16 uint4 segments
    for (int i = tid; i < 2048; i += 512) {
        const int f2 = i >> 4, seg = i & 15;
        *(uint4*)&W2s[f2 * 136 + seg * 8] = ((const uint4*)W2bf)[i];
    }
    if (tid < 64) dv[tid] = (n0 + tid < N) ? dinv[n0 + tid] : 0.f;

    // gather: 8 lanes per node (2 edge slots x 4 quarters), 8 nodes per wave
    {
        const int nd = lane >> 3, sub = lane & 7;
        const int slot = sub >> 2, qq = sub & 3;
        const int j = w * 8 + nd;
        const int n = n0 + j;
        float a[4] = {0.f, 0.f, 0.f, 0.f};
        if (n < N) {
            const int r1 = rowptr[n + 1];
            for (int e = rowptr[n] + slot; e < r1; e += 2)
                bf4acc(*(const uint2*)(xsb + (size_t)col[e] * 16 + qq * 4), a);
        }
#pragma unroll
        for (int i = 0; i < 4; ++i) a[i] += __shfl_xor(a[i], 4);
        if (slot == 0) {
            if (n < N) {   // self loop
                bf4acc(*(const uint2*)(xsb + (size_t)n * 16 + qq * 4), a);
                *(float4*)&arow[j * 16 + qq * 4] = make_float4(a[0], a[1], a[2], a[3]);
            } else {
                *(float4*)&arow[j * 16 + qq * 4] = make_float4(0.f, 0.f, 0.f, 0.f);
            }
        }
    }
    const int f = tid & 127, jg = tid >> 7;
    float w1r[16];
#pragma unroll
    for (int k = 0; k < 16; ++k) w1r[k] = W1[k * 128 + f];
    const float bias = b1[f];
    __syncthreads();

    // phase 1: h1 (bf16) into A-layout LDS
#pragma unroll 4
    for (int j = jg * 16; j < jg * 16 + 16; ++j) {
        float s = 0.f;
#pragma unroll
        for (int k = 0; k < 16; ++k) s += arow[j * 16 + k] * w1r[k];
        h1b[j * 136 + f] = bf1(fmaxf(dv[j] * s + bias, 0.f));
    }
    __syncthreads();

    // phase 2: MFMA, D[64x128] = h1[64x128] @ W2[128x128]
    const int mt = w & 3, nh = w >> 2;
    const int lm = lane & 15, quad = lane >> 4;
    f32x4 acc[4];
#pragma unroll
    for (int t = 0; t < 4; ++t) acc[t] = (f32x4){0.f, 0.f, 0.f, 0.f};
#pragma unroll
    for (int kb = 0; kb < 4; ++kb) {
        const short8 af = *(const short8*)&h1b[(mt * 16 + lm) * 136 + kb * 32 + quad * 8];
#pragma unroll
        for (int t = 0; t < 4; ++t) {
            const short8 bfv = *(const short8*)&W2s[(nh * 64 + t * 16 + lm) * 136 + kb * 32 + quad * 8];
            acc[t] = __builtin_amdgcn_mfma_f32_16x16x32_bf16(af, bfv, acc[t], 0, 0, 0);
        }
    }
    // epilogue: *dinv, quantize e5m2, store bytes
#pragma unroll
    for (int t = 0; t < 4; ++t) {
        const int f2 = nh * 64 + t * 16 + lm;
#pragma unroll
        for (int r = 0; r < 4; ++r) {
            const int j = mt * 16 + quad * 4 + r;
            const int n = n0 + j;
            if (n < N)
                ht1q[(size_t)n * 128 + f2] = e5m2q(acc[t][r] * dv[j]);
        }
    }
}

// Wave/node gather (2 halves x 32 lanes x uint(4 e5m2), 4x unroll -> 8
// rows in flight), then 8-node LDS run-merge (batch sorted) -> ~1 atomic
// set/block. Row = 128B e5m2; lane offset hoisted into hb.
__global__ __launch_bounds__(512) void k_gat128pool(
        const int* __restrict__ rowptr, const int* __restrict__ col,
        const unsigned char* __restrict__ ht1q,
        const float* __restrict__ dinv, const float* __restrict__ b2,
        const int* __restrict__ batch, float* __restrict__ gsum, int N) {
    __shared__ __align__(16) float h2s[8][128];
    __shared__ int bats[8];
    const int wave = threadIdx.x >> 6, lane = threadIdx.x & 63;
    const int half = lane >> 5, q = lane & 31;
    const int n = blockIdx.x * 8 + wave;
    const unsigned char* hb = ht1q + q * 4;    // lane's 4B column, hoisted
    float a[4] = {0.f, 0.f, 0.f, 0.f};
    if (n < N) {
        const int r0 = rowptr[n], r1 = rowptr[n + 1];
        int j = r0 + half;
        while (j + 6 < r1) {
            int s0 = col[j], s1 = col[j + 2], s2 = col[j + 4], s3 = col[j + 6];
            unsigned u0 = *(const unsigned*)(hb + ((size_t)s0 << 7));
            unsigned u1 = *(const unsigned*)(hb + ((size_t)s1 << 7));
            unsigned u2 = *(const unsigned*)(hb + ((size_t)s2 << 7));
            unsigned u3 = *(const unsigned*)(hb + ((size_t)s3 << 7));
            e5acc(u0, a); e5acc(u1, a); e5acc(u2, a); e5acc(u3, a);
            j += 8;
        }
        while (j < r1) {
            e5acc(*(const unsigned*)(hb + ((size_t)col[j] << 7)), a);
            j += 2;
        }
        if (half == 0)  // self loop
            e5acc(*(const unsigned*)(hb + ((size_t)n << 7)), a);
    }
#pragma unroll
    for (int i = 0; i < 4; ++i) a[i] += __shfl_xor(a[i], 32);
    if (half == 0) {
        if (n < N) {
            const float d = dinv[n];
            const float4 bb = *(const float4*)(b2 + q * 4);
            h2s[wave][q * 4 + 0] = fmaxf(a[0] * d + bb.x, 0.f);
            h2s[wave][q * 4 + 1] = fmaxf(a[1] * d + bb.y, 0.f);
            h2s[wave][q * 4 + 2] = fmaxf(a[2] * d + bb.z, 0.f);
            h2s[wave][q * 4 + 3] = fmaxf(a[3] * d + bb.w, 0.f);
            if (q == 0) bats[wave] = batch[n];
        } else {
            h2s[wave][q * 4 + 0] = 0.f; h2s[wave][q * 4 + 1] = 0.f;
            h2s[wave][q * 4 + 2] = 0.f; h2s[wave][q * 4 + 3] = 0.f;
            if (q == 0) bats[wave] = -1;
        }
    }
    __syncthreads();
    if (threadIdx.x < 32) {
        const int qq = threadIdx.x;
        int bprev = bats[0];
        float4 acc4 = *(const float4*)&h2s[0][qq * 4];
#pragma unroll
        for (int wv = 1; wv < 8; ++wv) {
            const int bw = bats[wv];   // wave-uniform branch (LDS scalar)
            const float4 rv = *(const float4*)&h2s[wv][qq * 4];
            if (bw == bprev) {
                acc4.x += rv.x; acc4.y += rv.y; acc4.z += rv.z; acc4.w += rv.w;
            } else {
                if (bprev >= 0) {
                    float* gs = gsum + (size_t)bprev * 128 + qq * 4;
                    unsafeAtomicAdd(gs + 0, acc4.x); unsafeAtomicAdd(gs + 1, acc4.y);
                    unsafeAtomicAdd(gs + 2, acc4.z); unsafeAtomicAdd(gs + 3, acc4.w);
                }
                bprev = bw; acc4 = rv;
            }
        }
        if (bprev >= 0) {
            float* gs = gsum + (size_t)bprev * 128 + qq * 4;
            unsafeAtomicAdd(gs + 0, acc4.x); unsafeAtomicAdd(gs + 1, acc4.y);
            unsafeAtomicAdd(gs + 2, acc4.z); unsafeAtomicAdd(gs + 3, acc4.w);
        }
    }
}

__global__ __launch_bounds__(128) void k_head(
        const float* __restrict__ gsum, const int* __restrict__ gptr,
        const float* __restrict__ Wlab, const float* __restrict__ blab,
        const float* __restrict__ Wd1, const float* __restrict__ bd1,
        const float* __restrict__ Wd2, const float* __restrict__ bd2,
        float* __restrict__ out, int G) {
    __shared__ float sp[128];
    __shared__ float red[128];
    __shared__ float hd[64];
    const int g = blockIdx.x, t = threadIdx.x;
    const float cnt = (float)(gptr[g + 1] - gptr[g]);
    const float invc = 1.f / fmaxf(cnt, 1.f);
    const float pooled = gsum[g * 128 + t] * invc;
    sp[t] = pooled;
    red[t] = pooled * Wlab[t];
    __syncthreads();
    for (int off = 64; off > 0; off >>= 1) {
        if (t < off) red[t] += red[t + off];
        __syncthreads();
    }
    if (t == 0) out[g] = 1.f / (1.f + expf(-(red[0] + blab[0])));
    __syncthreads();   // red[] reuse barrier (label reduce fully consumed)
    // domain hidden: 2-way split-K across all 128 threads
    const int tt = t & 63, kh = t >> 6;
    const int f0 = kh * 64;
    float ps = 0.f;
#pragma unroll 8
    for (int f = f0; f < f0 + 64; ++f) ps += sp[f] * Wd1[f * 64 + tt];
    red[t] = ps;
    __syncthreads();
    if (t < 64) hd[t] = fmaxf(red[t] + red[t + 64] + bd1[t], 0.f);
    __syncthreads();
    if (t < 2) {
        float s = bd2[t];
        for (int j = 0; j < 64; ++j) s += hd[j] * Wd2[j * 2 + t];
        out[G + g * 2 + t] = s;
    }
}

extern "C" void kernel_launch(void* const* d_in, const int* in_sizes, int n_in,
                              void* d_out, int out_size, void* d_ws, size_t ws_size,
                              hipStream_t stream) {
    const float* x     = (const float*)d_in[0];
    const int*   ei    = (const int*)d_in[1];   // [2,E]: ei[e]=src, ei[E+e]=dst
    const int*   batch = (const int*)d_in[2];
    const float* W1    = (const float*)d_in[3];
    const float* b1    = (const float*)d_in[4];
    const float* W2    = (const float*)d_in[5];
    const float* b2    = (const float*)d_in[6];
    const float* Wlab  = (const float*)d_in[7];
    const float* blab  = (const float*)d_in[8];
    const float* Wd1   = (const float*)d_in[9];
    const float* bd1   = (const float*)d_in[10];
    const float* Wd2   = (const float*)d_in[11];
    const float* bd2   = (const float*)d_in[12];
    float* out = (float*)d_out;

    const int N = in_sizes[0] / 16;
    const int E = in_sizes[1] / 2;
    const int G = out_size / 3;
    const int NB = (N + 255) >> 8;             // node buckets of 256

    char* p = (char*)d_ws;
    auto carve = [&](size_t bytes) {
        void* r = (void*)p;
        p += (bytes + 255) & ~(size_t)255;
        return r;
    };
    int*      bcnt   = (int*)     carve(256 * 4);
    unsigned* col1   = (unsigned*)carve((size_t)NB * BCAP * 4);
    int*      col    = (int*)     carve((size_t)E * 4);
    int*      rowptr = (int*)     carve((size_t)(N + 1) * 4);
    int*      gptr   = (int*)     carve((size_t)(G + 1) * 4);
    float*    dinv   = (float*)   carve((size_t)N * 4);
    unsigned short* xsb  = (unsigned short*)carve((size_t)N * 16 * 2);
    unsigned short* W2bf = (unsigned short*)carve(128 * 128 * 2);
    unsigned char*  ht1q = (unsigned char*) carve((size_t)N * 128);
    float*    gsum   = (float*)   carve((size_t)G * 128 * 4);

    const int FB = (E + TILE - 1) / TILE;      // bfill: one LDS tile/block

    hipMemsetAsync(bcnt, 0, 256 * 4, stream);
    k_bfill  <<<FB, 512, 0, stream>>>(ei, bcnt, col1, batch, gptr, gsum, W2,
                                      W2bf, E, NB, N, G);
    k_bsort  <<<NB, 512, 0, stream>>>(col1, bcnt, col, rowptr, dinv, x, xsb,
                                      N, E, NB);
    k_l12g   <<<(N + 63) / 64, 512, 0, stream>>>(rowptr, col, xsb, dinv,
                                                 W1, b1, W2bf, ht1q, N);
    k_gat128pool<<<(N + 7) / 8, 512, 0, stream>>>(rowptr, col, ht1q, dinv, b2,
                                                  batch, gsum, N);
    k_head   <<<G, 128, 0, stream>>>(gsum, gptr, Wlab, blab, Wd1, bd1, Wd2,
                                     bd2, out, G);
}